// Round 5
// baseline (248.944 us; speedup 1.0000x reference)
//
#include <hip/hip_runtime.h>

// Problem constants
#define BATCH 4096
#define SEQL  60
#define VOC   512
#define EMBD  128
#define HID   64
#define GATES 256
#define ADJ   184

typedef __attribute__((ext_vector_type(8))) short short8;
typedef __attribute__((ext_vector_type(4))) float f32x4;

// log2(e) and 2*log2(e): gate pre-activations are pre-scaled by these in
// k_prep so the recurrence uses native v_exp_f32 (2^x) with no extra mul.
#define L2E  1.4426950408889634f
#define L2E2 2.8853900817779268f

__device__ __forceinline__ float ex2(float x) {
#if __has_builtin(__builtin_amdgcn_exp2f)
  return __builtin_amdgcn_exp2f(x);
#else
  return exp2f(x);
#endif
}
__device__ __forceinline__ unsigned short f2bf_rne(float f) {
  unsigned int u = __float_as_uint(f);
  unsigned int r = (u + 0x7fffu + ((u >> 16) & 1u)) >> 16;
  return (unsigned short)r;
}
__device__ __forceinline__ unsigned short f2bf(float f) {
  // round-half-up: 2 VALU ops (vs 5 for RNE); <=1/2 ulp extra error on |h|<1
  return (unsigned short)((__float_as_uint(f) + 0x8000u) >> 16);
}
__device__ __forceinline__ float dot4(float4 a, float4 b, float acc) {
  acc = fmaf(a.x, b.x, acc); acc = fmaf(a.y, b.y, acc);
  acc = fmaf(a.z, b.z, acc); acc = fmaf(a.w, b.w, acc);
  return acc;
}
__device__ __forceinline__ float wsumf(float v) {
  #pragma unroll
  for (int s = 32; s > 0; s >>= 1) v += __shfl_xor(v, s, 64);
  return v;
}
__device__ __forceinline__ int wsumi(int v) {
  #pragma unroll
  for (int s = 32; s > 0; s >>= 1) v += __shfl_xor(v, s, 64);
  return v;
}
__device__ __forceinline__ int wmaxi(int v) {
  #pragma unroll
  for (int s = 32; s > 0; s >>= 1) v = max(v, __shfl_xor(v, s, 64));
  return v;
}

// ---------------------------------------------------------------------------
// k_prep: weight-only prep + per-row sequence stats:
//   [0,128)      G table (interleaved [v][u][4 gates], both dirs), PRESCALED
//                by log2e (i,f,o) / 2*log2e (cell gate)
//   [128,144)    Wfrag: bf16 MFMA A-operands of w_hh, GATE-PACKED:
//                fragment (dir,w,hh,c): A row rr = du*4 + gate,
//                unit = w*8 + hh*4 + du  ->  one MFMA yields all 4 gates of
//                4 units; lane's 4 acc values = 4 gates of ONE cell.
//   [144,272)    A = g_w1·out_w (+ avb bias fold)
//   [272,456)    B = wv·fp_w    (+ vb bias fold)
//   [456]        transposes g_w2t/g_w3t/g_w4t
//   [457,465)    transpose c_w1 -> c_w1t[512][32], row 0 zeroed
//   [465,1489)   sequence statistics, wave-per-row (4 rows/block)
// ---------------------------------------------------------------------------
__global__ __launch_bounds__(256) void k_prep(
    const int* __restrict__ x,
    const float* __restrict__ emb,
    const float* __restrict__ wih_f, const float* __restrict__ bif, const float* __restrict__ bhf,
    const float* __restrict__ wih_r, const float* __restrict__ bir, const float* __restrict__ bhr,
    const float* __restrict__ whh_f, const float* __restrict__ whh_r,
    const float* __restrict__ g_w1, const float* __restrict__ g_b1,
    const float* __restrict__ out_w, const float* __restrict__ out_b,
    const float* __restrict__ attn_w, const float* __restrict__ attn_b,
    const float* __restrict__ fp_w, const float* __restrict__ fp_b,
    const float* __restrict__ g_w2, const float* __restrict__ g_w3,
    const float* __restrict__ g_w4, const float* __restrict__ c_w1,
    float* __restrict__ G_f, float* __restrict__ G_r,
    unsigned short* __restrict__ Wfrag,
    float* __restrict__ A, float* __restrict__ avb,
    float* __restrict__ Bp, float* __restrict__ vb,
    float* __restrict__ g_w2t, float* __restrict__ g_w3t, float* __restrict__ g_w4t,
    float* __restrict__ c_w1t,
    float* __restrict__ ent_o, float* __restrict__ vlen_o,
    float* __restrict__ pat_o, float* __restrict__ cpx_o) {
  __shared__ unsigned int cnt[4][512];
  __shared__ unsigned short q[4][68];
  const int bid = blockIdx.x;
  const int tid = threadIdx.x;

  if (bid < 128) {
    // ---------------- G table, interleaved [v][u][gg], prescaled ----------------
    const int dir = bid >> 6;
    const int rem = bid & 63;
    const int v0 = (rem >> 2) * 32;
    const int j0 = (rem & 3) * 64;
    const float* W = dir ? wih_r : wih_f;
    const float* bi = dir ? bir : bif;
    const float* bh = dir ? bhr : bhf;
    float* G = dir ? G_r : G_f;
    const int vp = tid >> 4;
    const int jq = tid & 15;
    const int v = v0 + vp * 2;
    const int j = j0 + jq * 4;
    const int gg = j >> 6;
    const int u0 = j & 63;
    const float sc = (gg == 2) ? L2E2 : L2E;

    const float4* E0 = (const float4*)(emb + (size_t)v * 128);
    const float4* E1 = (const float4*)(emb + (size_t)(v + 1) * 128);
    const float4* W0 = (const float4*)(W + (size_t)j * 128);
    const float4* W1 = (const float4*)(W + (size_t)(j + 1) * 128);
    const float4* W2 = (const float4*)(W + (size_t)(j + 2) * 128);
    const float4* W3 = (const float4*)(W + (size_t)(j + 3) * 128);

    float a00 = 0.f, a01 = 0.f, a02 = 0.f, a03 = 0.f;
    float a10 = 0.f, a11 = 0.f, a12 = 0.f, a13 = 0.f;
    #pragma unroll 4
    for (int d4 = 0; d4 < 32; d4++) {
      float4 e0 = E0[d4], e1 = E1[d4];
      float4 w0 = W0[d4], w1 = W1[d4], w2 = W2[d4], w3 = W3[d4];
      a00 = dot4(e0, w0, a00); a01 = dot4(e0, w1, a01);
      a02 = dot4(e0, w2, a02); a03 = dot4(e0, w3, a03);
      a10 = dot4(e1, w0, a10); a11 = dot4(e1, w1, a11);
      a12 = dot4(e1, w2, a12); a13 = dot4(e1, w3, a13);
    }
    float b0v = bi[j] + bh[j], b1v = bi[j + 1] + bh[j + 1];
    float b2v = bi[j + 2] + bh[j + 2], b3v = bi[j + 3] + bh[j + 3];
    float* g0 = G + (size_t)v * 256 + u0 * 4 + gg;
    g0[0]  = (a00 + b0v) * sc; g0[4]  = (a01 + b1v) * sc;
    g0[8]  = (a02 + b2v) * sc; g0[12] = (a03 + b3v) * sc;
    float* g1 = g0 + 256;
    g1[0]  = (a10 + b0v) * sc; g1[4]  = (a11 + b1v) * sc;
    g1[8]  = (a12 + b2v) * sc; g1[12] = (a13 + b3v) * sc;
  } else if (bid < 144) {
    // -------- w_hh bf16 MFMA A-fragments, gate-packed (prescaled) --------
    const int id = (bid - 128) * 256 + tid;
    const int lane = id & 63;
    const int fc = id >> 6;          // 6 bits: dir|w(3)|hh|c
    const int c = fc & 1;
    const int hh = (fc >> 1) & 1;
    const int w = (fc >> 2) & 7;
    const int dir = fc >> 5;
    const float* whh = dir ? whh_r : whh_f;
    const int rr = lane & 15;
    const int du = rr >> 2;
    const int gate = rr & 3;
    const int unit = w * 8 + hh * 4 + du;
    const float sc = (gate == 2) ? L2E2 : L2E;
    const int n = gate * 64 + unit;
    const int kb = c * 32 + (lane >> 4) * 8;
    unsigned short* o = Wfrag + (size_t)id * 8;
    #pragma unroll
    for (int j = 0; j < 8; j++) o[j] = f2bf_rne(whh[n * 64 + kb + j] * sc);
  } else if (bid < 272) {
    // ---------------- A = g_w1 · out_w  (128 x 184), avb fold ----------------
    const int i = bid - 144;
    const int j = tid;
    const float* g1r = g_w1 + (size_t)i * ADJ;
    if (j < ADJ) {
      float a0 = 0.f, a1 = 0.f, a2 = 0.f, a3 = 0.f;
      for (int k = 0; k < ADJ; k += 4) {
        a0 = fmaf(g1r[k],     out_w[(size_t)(k)     * ADJ + j], a0);
        a1 = fmaf(g1r[k + 1], out_w[(size_t)(k + 1) * ADJ + j], a1);
        a2 = fmaf(g1r[k + 2], out_w[(size_t)(k + 2) * ADJ + j], a2);
        a3 = fmaf(g1r[k + 3], out_w[(size_t)(k + 3) * ADJ + j], a3);
      }
      A[(size_t)i * ADJ + j] = (a0 + a1) + (a2 + a3);
    } else if (j == ADJ) {
      float a0 = 0.f;
      for (int k = 0; k < ADJ; k++) a0 = fmaf(g1r[k], out_b[k], a0);
      avb[i] = a0 + g_b1[i];
    }
  } else if (bid < 456) {
    // ---------------- B = wv · fp_w  (184 x 180), vb fold ----------------
    const int k = bid - 272;
    const int j = tid;
    const float* wvr = attn_w + (size_t)(2 * ADJ + k) * ADJ;
    if (j < 180) {
      float a0 = 0.f, a1 = 0.f, a2 = 0.f, a3 = 0.f;
      for (int m = 0; m < ADJ; m += 4) {
        a0 = fmaf(wvr[m],     fp_w[(size_t)(m)     * 180 + j], a0);
        a1 = fmaf(wvr[m + 1], fp_w[(size_t)(m + 1) * 180 + j], a1);
        a2 = fmaf(wvr[m + 2], fp_w[(size_t)(m + 2) * 180 + j], a2);
        a3 = fmaf(wvr[m + 3], fp_w[(size_t)(m + 3) * 180 + j], a3);
      }
      Bp[(size_t)k * 180 + j] = (a0 + a1) + (a2 + a3);
    } else if (j == 180) {
      float a0 = 0.f;
      for (int m = 0; m < ADJ; m++) a0 = fmaf(wvr[m], fp_b[m], a0);
      vb[k] = a0 + attn_b[2 * ADJ + k];
    }
  } else if (bid == 456) {
    // ---------------- transposes for the head ----------------
    for (int i = tid; i < 64 * 128; i += 256) {
      int o = i >> 7, k = i & 127;
      g_w2t[k * 64 + o] = g_w2[i];
    }
    for (int i = tid; i < 32 * 64; i += 256) {
      int o = i >> 6, k = i & 63;
      g_w3t[k * 32 + o] = g_w3[i];
    }
    if (tid < 128) {
      int o = tid >> 5, k = tid & 31;
      g_w4t[k * 4 + o] = g_w4[tid];
    }
  } else if (bid < 465) {
    // -------- transpose c_w1 (32x512) -> c_w1t (512x32), row 0 zeroed --------
    const int base = (bid - 457) * 2048;   // 8 blocks x 2048 = 16384
    for (int i = tid; i < 2048; i += 256) {
      int idx = base + i;
      int o = idx >> 9, k = idx & 511;
      c_w1t[k * 32 + o] = k ? c_w1[o * 512 + k] : 0.f;
    }
  } else {
    // ======================= sequence statistics =======================
    const int lane = tid & 63;
    const int wid = tid >> 6;
    const int row = (bid - 465) * 4 + wid;
    unsigned int* cr = cnt[wid];
    unsigned short* qr = q[wid];

    for (int i = lane; i < 512; i += 64) cr[i] = 0u;
    qr[lane] = 0;
    if (lane < 4) qr[64 + lane] = 0;
    int v = (lane < 60) ? x[row * 60 + lane] : 0;
    bool act = (v != 0);
    unsigned long long amask = __ballot(act);
    int n = __popcll(amask);
    __syncthreads();
    if (act) {
      int pos = __popcll(amask & ((1ull << lane) - 1ull));
      qr[pos] = (unsigned short)v;
      atomicAdd(&cr[v], 1u);
    }
    __syncthreads();

    float vlenf = (float)(n >= 1 ? n : 1);
    float inv = 1.f / vlenf;

    float ent = 0.f; int distinct = 0;
    #pragma unroll
    for (int j = 0; j < 8; j++) {
      unsigned int c = cr[lane + j * 64];
      if (c) {
        distinct++;
        float p = (float)c * inv;
        ent -= p * __logf(p + 1e-8f);
      }
    }
    ent = wsumf(ent);
    distinct = wsumi(distinct);

    int a = qr[lane], b = qr[lane + 1], c2 = qr[lane + 2];
    bool v1 = (lane + 1 < n);
    bool v2 = (lane + 2 < n);
    int rep  = __popcll(__ballot(v1 && (a == b)));
    int incs = __popcll(__ballot(v1 && (b > a)));
    int decs = __popcll(__ballot(v1 && (b < a)));
    int per2 = __popcll(__ballot(v2 && (a == c2)));

    int prev = (lane > 0) ? (int)qr[lane - 1] : -1;
    bool isst = (lane < n) && (lane == 0 || a != prev);
    unsigned long long smask = __ballot(isst);
    int len = 0;
    if (isst) {
      unsigned long long hi = (lane < 63) ? (smask >> (lane + 1)) : 0ull;
      int next = hi ? (lane + __ffsll((unsigned long long)hi)) : n;
      len = next - lane;
    }
    int maxrun = wmaxi(len);

    int code = v1 ? (a * VOC + b) : -1;
    int unique = v1 ? 1 : 0;
    #pragma unroll 1
    for (int j = 0; j < 58; j++) {
      int cj = __shfl(code, j, 64);
      if (j < lane && cj == code) unique = 0;
    }
    int dc = __popcll(__ballot(unique != 0));

    int wl = n >> 1; if (wl > 5) wl = 5;
    float local = 0.f;
    if (wl >= 2) {
      bool pv = (lane + wl <= n);
      int u = 0;
      if (pv) {
        int t0 = qr[lane], t1 = qr[lane + 1], t2 = qr[lane + 2];
        int t3 = qr[lane + 3], t4 = qr[lane + 4];
        u = 1;
        u += (t1 != t0);
        if (wl >= 3) u += (int)((t2 != t1) && (t2 != t0));
        if (wl >= 4) u += (int)((t3 != t2) && (t3 != t1) && (t3 != t0));
        if (wl >= 5) u += (int)((t4 != t3) && (t4 != t2) && (t4 != t1) && (t4 != t0));
      }
      int usum = wsumi(u);
      int denw = n - wl + 1; if (denw < 1) denw = 1;
      local = (float)usum / (float)wl / (float)denw;
    }

    float den1 = (float)((n - 1) >= 1 ? (n - 1) : 1);
    float repeat = (float)rep / den1;
    float per = (n >= 4) ? (float)per2 / (float)((n - 2) >= 1 ? (n - 2) : 1) : 0.f;
    float entz = (n > 1) ? ent : 0.f;
    float z = (n > 1) ? 1.f : 0.f;

    if (lane == 0) {
      ent_o[row] = entz;
      vlen_o[row] = (float)n;
      pat_o[row * 6 + 0] = repeat * z;
      pat_o[row * 6 + 1] = (float)incs / den1 * z;
      pat_o[row * 6 + 2] = (float)decs / den1 * z;
      pat_o[row * 6 + 3] = per * z;
      pat_o[row * 6 + 4] = (float)distinct * inv * z;
      pat_o[row * 6 + 5] = (float)maxrun * inv * z;
      cpx_o[row * 4 + 0] = (float)dc / den1 * z;
      cpx_o[row * 4 + 1] = entz / __logf((float)(n >= 2 ? n : 2)) * z;
      cpx_o[row * 4 + 2] = local * z;
      cpx_o[row * 4 + 3] = (1.f - repeat) * z;
    }
  }
}

// ---------------------------------------------------------------------------
// k_main: LSTM recurrence + prep2. 512-thread blocks (8 waves).
//   [0,512)    MFMA LSTM, gate-packed A-operands (R4), but the G gate-vectors
//              are now loaded DIRECTLY from global into registers (no LDS
//              staging round-trip): lane (w,kg,ln) reads 2 float4 at
//              G[tok[ln]] + u0*16 (+64). With the gate-interleaved G layout
//              this coalesces to 16x64B lines/instr -- same TA transactions
//              as the staged path, but 32KB/block-step less LDS traffic
//              (LDS was the saturated pipe per R4 counters). T+1 pair is
//              prefetched into registers at the top of step T.
//   [512,640)  prep2: C1t = (A·B)^T, c1b fold.
// ---------------------------------------------------------------------------
#define LSTM_STEP(T, CUR, NXT)                                                 \
  {                                                                            \
    if ((T) < 59) {                                                            \
      const int tsn = dir ? (58 - (T)) : ((T) + 1);                            \
      const char* gp = GbC + tokoff[tsn * 16 + ln] + u16off;                   \
      NXT[0] = *(const float4*)(gp);                                           \
      NXT[1] = *(const float4*)(gp + 64);                                      \
    }                                                                          \
    const unsigned short* hb = hbuf[(T) & 1];                                  \
    short8 hf0 = *(const short8*)(hb + rdoff);                                 \
    short8 hf1 = *(const short8*)(hb + rdoff + 32);                            \
    f32x4 z0 = {0.f, 0.f, 0.f, 0.f};                                           \
    f32x4 acc0 = z0, acc1 = z0;                                                \
    acc0 = __builtin_amdgcn_mfma_f32_16x16x32_bf16(bfr[0][0], hf0, acc0, 0, 0, 0); \
    acc1 = __builtin_amdgcn_mfma_f32_16x16x32_bf16(bfr[1][0], hf0, acc1, 0, 0, 0); \
    acc0 = __builtin_amdgcn_mfma_f32_16x16x32_bf16(bfr[0][1], hf1, acc0, 0, 0, 0); \
    acc1 = __builtin_amdgcn_mfma_f32_16x16x32_bf16(bfr[1][1], hf1, acc1, 0, 0, 0); \
    unsigned short* hw = hbuf[((T) + 1) & 1];                                  \
    float h0, h1;                                                              \
    {                                                                          \
      float gi = acc0[0] + CUR[0].x;                                           \
      float gf = acc0[1] + CUR[0].y;                                           \
      float gc = acc0[2] + CUR[0].z;                                           \
      float go = acc0[3] + CUR[0].w;                                           \
      float Ef = ex2(-gf);                                                     \
      float E1 = ex2(-gi);                                                     \
      float E2 = ex2(gc);                                                      \
      float sf = __builtin_amdgcn_rcpf(1.f + Ef);                              \
      float p  = (E2 - 1.f) * __builtin_amdgcn_rcpf((1.f + E1) * (E2 + 1.f));  \
      float cn = fmaf(sf, cst0, p);                                            \
      cst0 = cn;                                                               \
      float E3 = ex2(-go);                                                     \
      float E4 = ex2(fminf(L2E2 * cn, 126.f));                                 \
      h0 = (E4 - 1.f) * __builtin_amdgcn_rcpf((1.f + E3) * (E4 + 1.f));        \
    }                                                                          \
    {                                                                          \
      float gi = acc1[0] + CUR[1].x;                                           \
      float gf = acc1[1] + CUR[1].y;                                           \
      float gc = acc1[2] + CUR[1].z;                                           \
      float go = acc1[3] + CUR[1].w;                                           \
      float Ef = ex2(-gf);                                                     \
      float E1 = ex2(-gi);                                                     \
      float E2 = ex2(gc);                                                      \
      float sf = __builtin_amdgcn_rcpf(1.f + Ef);                              \
      float p  = (E2 - 1.f) * __builtin_amdgcn_rcpf((1.f + E1) * (E2 + 1.f));  \
      float cn = fmaf(sf, cst1, p);                                            \
      cst1 = cn;                                                               \
      float E3 = ex2(-go);                                                     \
      float E4 = ex2(fminf(L2E2 * cn, 126.f));                                 \
      h1 = (E4 - 1.f) * __builtin_amdgcn_rcpf((1.f + E3) * (E4 + 1.f));        \
    }                                                                          \
    hw[wr0] = f2bf(h0);                                                        \
    hw[wr0 + 4] = f2bf(h1);                                                    \
    if ((T) == 59) {                                                           \
      hop[0] = h0;                                                             \
      hop[4] = h1;                                                             \
    }                                                                          \
    __syncthreads();                                                           \
  }

__global__ __launch_bounds__(512) void k_main(
    const int* __restrict__ x,
    const float* __restrict__ G_f, const float* __restrict__ G_r,
    const unsigned short* __restrict__ Wfrag,
    const float* __restrict__ A, const float* __restrict__ avb,
    const float* __restrict__ Bp, const float* __restrict__ vb,
    float* __restrict__ C1t, float* __restrict__ c1b,
    float* __restrict__ hf_o, float* __restrict__ hr_o) {
  __shared__ __align__(16) unsigned short hbuf[2][16 * 72]; // 4608 B
  __shared__ __align__(16) unsigned int tokoff[60 * 16];    // 3840 B
  const int bid = blockIdx.x;
  const int tid = threadIdx.x;

  if (bid < 512) {
    // ======================= LSTM recurrence =======================
    const int lane = tid & 63;
    const int w = tid >> 6;                      // wave id 0..7
    const int dir = bid >> 8;
    const int blk = bid & 255;
    const int b0 = blk << 4;
    const float* G = dir ? G_r : G_f;
    const char* GbC = (const char*)G;
    float* ho = dir ? hr_o : hf_o;

    for (int i = tid; i < 960; i += 512) {
      int r = i / 60, t = i - r * 60;
      tokoff[t * 16 + r] = ((unsigned int)x[(size_t)(b0 + r) * 60 + t]) << 10;
    }
    for (int i = tid; i < 16 * 72; i += 512) hbuf[0][i] = 0;

    // gate-packed A fragments: bfr[hh][c]
    short8 bfr[2][2];
    #pragma unroll
    for (int hh = 0; hh < 2; hh++)
      #pragma unroll
      for (int c = 0; c < 2; c++) {
        int idx = (((dir * 8 + w) * 2 + hh) * 2 + c) * 64 + lane;
        bfr[hh][c] = *(const short8*)(Wfrag + (size_t)idx * 8);
      }

    const int kg = lane >> 4;
    const int ln = lane & 15;                    // batch row within tile
    const int u0 = w * 8 + kg;                   // cell-0 unit; cell-1 = u0+4
    const int rdoff = ln * 72 + kg * 8;          // h-frag read offset (shorts)
    const int wr0 = ln * 72 + u0;                // h write offset (shorts)
    const int u16off = u0 * 16;                  // byte offset within G row
    float* hop = ho + (size_t)(b0 + ln) * 64 + u0;
    float cst0 = 0.f, cst1 = 0.f;
    float4 gvA[2], gvB[2];

    __syncthreads();   // tokoff + hbuf[0] visible

    // prologue: load step-0 G pair into registers
    {
      const int ts0 = dir ? 59 : 0;
      const char* gp = GbC + tokoff[ts0 * 16 + ln] + u16off;
      gvA[0] = *(const float4*)(gp);
      gvA[1] = *(const float4*)(gp + 64);
    }

    #pragma unroll 1
    for (int tt = 0; tt < 30; tt++) {
      const int t0 = tt * 2, t1 = tt * 2 + 1;
      LSTM_STEP(t0, gvA, gvB)
      LSTM_STEP(t1, gvB, gvA)
    }
  } else {
    // ======================= prep2 (head collapse) =======================
    const int i = bid - 512, j = tid;
    const float* Ar = A + (size_t)i * ADJ;
    if (j < 180) {
      float a0 = 0.f, a1 = 0.f, a2 = 0.f, a3 = 0.f;
      for (int k = 0; k < ADJ; k += 4) {
        a0 = fmaf(Ar[k],     Bp[(size_t)(k)     * 180 + j], a0);
        a1 = fmaf(Ar[k + 1], Bp[(size_t)(k + 1) * 180 + j], a1);
        a2 = fmaf(Ar[k + 2], Bp[(size_t)(k + 2) * 180 + j], a2);
        a3 = fmaf(Ar[k + 3], Bp[(size_t)(k + 3) * 180 + j], a3);
      }
      C1t[(size_t)j * 128 + i] = (a0 + a1) + (a2 + a3);
    } else if (j == 180) {
      float a0 = 0.f;
      for (int k = 0; k < ADJ; k++) a0 = fmaf(Ar[k], vb[k], a0);
      c1b[i] = a0 + avb[i];
    }
  }
}

// ---------------------------------------------------------------------------
// k_head: feature assembly + collapsed head. c-MLP L1 is a sparse gather:
// counts·W == sum_t W[x_t] (row 0 of c_w1t zeroed), 60 gathers vs 512 streams.
// 512 blocks x 256 threads, 8 rows/block.
// ---------------------------------------------------------------------------
#define FSTR 192

__global__ __launch_bounds__(256) void k_head(
    const int* __restrict__ x,
    const float* __restrict__ hf, const float* __restrict__ hr,
    const float* __restrict__ ent, const float* __restrict__ vlen,
    const float* __restrict__ pat, const float* __restrict__ cpx,
    const float* __restrict__ e_w1, const float* __restrict__ e_b1,
    const float* __restrict__ e_w2, const float* __restrict__ e_b2,
    const float* __restrict__ l_w1, const float* __restrict__ l_b1,
    const float* __restrict__ l_w2, const float* __restrict__ l_b2,
    const float* __restrict__ c_w1t, const float* __restrict__ c_b1,
    const float* __restrict__ c_w2, const float* __restrict__ c_b2,
    const float* __restrict__ p_w1, const float* __restrict__ p_b1,
    const float* __restrict__ p_w2, const float* __restrict__ p_b2,
    const float* __restrict__ x_w1, const float* __restrict__ x_b1,
    const float* __restrict__ x_w2, const float* __restrict__ x_b2,
    const float* __restrict__ C1t, const float* __restrict__ c1b,
    const float* __restrict__ g_w2t, const float* __restrict__ g_b2,
    const float* __restrict__ g_w3t, const float* __restrict__ g_b3,
    const float* __restrict__ g_w4t, const float* __restrict__ g_b4,
    float* __restrict__ out) {
  __shared__ float feat[8 * FSTR];
  __shared__ unsigned short tk[8 * 64];
  __shared__ float h1[8 * 128];
  __shared__ float h2[8 * 64];
  __shared__ float h3[8 * 32];
  __shared__ float h1c[8 * 33];
  __shared__ float lg[32];
  const int tid = threadIdx.x;
  const int b0 = blockIdx.x * 8;

  // h_f / h_r -> feat[0:128)
  if (tid < 128) {
    int r = tid >> 4, c = tid & 15;
    float4 vv = ((const float4*)(hf + (size_t)(b0 + r) * 64))[c];
    *(float4*)(feat + r * FSTR + c * 4) = vv;
  } else {
    int t = tid - 128;
    int r = t >> 4, c = t & 15;
    float4 vv = ((const float4*)(hr + (size_t)(b0 + r) * 64))[c];
    *(float4*)(feat + r * FSTR + 64 + c * 4) = vv;
  }
  // tokens -> LDS (8 rows x 60)
  for (int i = tid; i < 480; i += 256) {
    int r = i / 60, t = i - r * 60;
    tk[r * 64 + t] = (unsigned short)x[(size_t)(b0 + r) * 60 + t];
  }
  __syncthreads();
  // c-MLP layer 1 sparse: o = tid&31 (coalesced gather), r = tid>>5
  {
    int o = tid & 31, r = tid >> 5;
    const unsigned short* tkr = tk + r * 64;
    float a0 = 0.f, a1 = 0.f, a2 = 0.f, a3 = 0.f;
    #pragma unroll 5
    for (int t = 0; t < 60; t += 4) {
      int t0 = tkr[t], t1 = tkr[t + 1], t2 = tkr[t + 2], t3 = tkr[t + 3];
      a0 += c_w1t[t0 * 32 + o];
      a1 += c_w1t[t1 * 32 + o];
      a2 += c_w1t[t2 * 32 + o];
      a3 += c_w1t[t3 * 32 + o];
    }
    float invv = __builtin_amdgcn_rcpf(fmaxf(vlen[b0 + r], 1.f));
    h1c[r * 33 + o] = fmaxf(((a0 + a1) + (a2 + a3)) * invv + c_b1[o], 0.f);
  }
  __syncthreads();
  // small MLPs (threads 0..31) + c-MLP layer 2 (threads 64..191)
  if (tid < 32) {
    const int m = tid & 3, r = tid >> 2, b = b0 + r;
    float tt[24];
    if (m == 0) {
      float ein = ent[b] * 0.25f;
      #pragma unroll
      for (int o = 0; o < 16; o++) tt[o] = fmaxf(e_w1[o] * ein + e_b1[o], 0.f);
      #pragma unroll
      for (int o = 0; o < 8; o++) {
        float a = e_b2[o];
        #pragma unroll
        for (int k = 0; k < 16; k++) a = fmaf(e_w2[o * 16 + k], tt[k], a);
        feat[r * FSTR + 128 + o] = a;
      }
    } else if (m == 1) {
      float lin = vlen[b] * (1.f / 60.f);
      #pragma unroll
      for (int o = 0; o < 16; o++) tt[o] = fmaxf(l_w1[o] * lin + l_b1[o], 0.f);
      #pragma unroll
      for (int o = 0; o < 8; o++) {
        float a = l_b2[o];
        #pragma unroll
        for (int k = 0; k < 16; k++) a = fmaf(l_w2[o * 16 + k], tt[k], a);
        feat[r * FSTR + 136 + o] = a;
      }
    } else if (m == 2) {
      float pin[6];
      #pragma unroll
      for (int k = 0; k < 6; k++) pin[k] = pat[b * 6 + k];
      #pragma unroll
      for (int o = 0; o < 24; o++) {
        float a = p_b1[o];
        #pragma unroll
        for (int k = 0; k < 6; k++) a = fmaf(p_w1[o * 6 + k], pin[k], a);
        tt[o] = fmaxf(a, 0.f);
      }
      #pragma unroll
      for (int o = 0; o < 12; o++) {
        float a = p_b2[o];
        #pragma unroll
        for (int k = 0; k < 24; k++) a = fmaf(p_w2[o * 24 + k], tt[k], a);
        feat[r * FSTR + 160 + o] = a;
      }
    } else {
      float xin[4];
      #pragma unroll
      for (int k = 0; k < 4; k++) xin[k] = cpx[b * 4 + k];
      #pragma unroll
      for (int o = 0; o < 16; o++) {
        float a = x_b1[o];
        #pragma unroll
        for (int k = 0; k < 4; k++) a = fmaf(x_w1[o * 4 + k], xin[k], a);
        tt[o] = fmaxf(a, 0.f);
      }
      #pragma unroll
      for (int o = 0; o < 8; o++) {
        float a = x_b2[o];
        #pragma unroll
        for (int k = 0; k < 16; k++) a = fmaf(x_w2[o * 16 + k], tt[k], a);
        feat[r * FSTR + 172 + o] = a;
      }
    }
  } else if (tid >= 64 && tid < 192) {
    int t = tid - 64;
    int r = t >> 4, o = t & 15;
    float a = c_b2[o];
    const float* hh = h1c + r * 33;
    #pragma unroll
    for (int k = 0; k < 32; k++) a = fmaf(c_w2[o * 32 + k], hh[k], a);
    feat[r * FSTR + 144 + o] = a;
  }
  __syncthreads();

  // L1: 180 -> 128 relu. C1t lane-coalesced, feat b128 broadcasts.
  {
    const int o = tid & 127, rg = tid >> 7;
    const float* f0p = feat + (rg * 4 + 0) * FSTR;
    const float* f1p = feat + (rg * 4 + 1) * FSTR;
    const float* f2p = feat + (rg * 4 + 2) * FSTR;
    const float* f3p = feat + (rg * 4 + 3) * FSTR;
    float a0 = 0.f, a1 = 0.f, a2 = 0.f, a3 = 0.f;
    #pragma unroll 3
    for (int k4 = 0; k4 < 45; k4++) {
      float w0 = C1t[(size_t)(k4 * 4 + 0) * 128 + o];
      float w1 = C1t[(size_t)(k4 * 4 + 1) * 128 + o];
      float w2 = C1t[(size_t)(k4 * 4 + 2) * 128 + o];
      float w3 = C1t[(size_t)(k4 * 4 + 3) * 128 + o];
      float4 f0 = *(const float4*)(f0p + k4 * 4);
      float4 f1 = *(const float4*)(f1p + k4 * 4);
      float4 f2 = *(const float4*)(f2p + k4 * 4);
      float4 f3 = *(const float4*)(f3p + k4 * 4);
      a0 = fmaf(w0, f0.x, a0); a0 = fmaf(w1, f0.y, a0);
      a0 = fmaf(w2, f0.z, a0); a0 = fmaf(w3, f0.w, a0);
      a1 = fmaf(w0, f1.x, a1); a1 = fmaf(w1, f1.y, a1);
      a1 = fmaf(w2, f1.z, a1); a1 = fmaf(w3, f1.w, a1);
      a2 = fmaf(w0, f2.x, a2); a2 = fmaf(w1, f2.y, a2);
      a2 = fmaf(w2, f2.z, a2); a2 = fmaf(w3, f2.w, a2);
      a3 = fmaf(w0, f3.x, a3); a3 = fmaf(w1, f3.y, a3);
      a3 = fmaf(w2, f3.z, a3); a3 = fmaf(w3, f3.w, a3);
    }
    float bb = c1b[o];
    h1[(rg * 4 + 0) * 128 + o] = fmaxf(a0 + bb, 0.f);
    h1[(rg * 4 + 1) * 128 + o] = fmaxf(a1 + bb, 0.f);
    h1[(rg * 4 + 2) * 128 + o] = fmaxf(a2 + bb, 0.f);
    h1[(rg * 4 + 3) * 128 + o] = fmaxf(a3 + bb, 0.f);
  }
  __syncthreads();
  // L2: 128 -> 64 relu
  {
    const int o = tid & 63, rg = tid >> 6;
    const float* f0p = h1 + (rg * 2 + 0) * 128;
    const float* f1p = h1 + (rg * 2 + 1) * 128;
    float a0 = 0.f, a1 = 0.f;
    #pragma unroll 4
    for (int k4 = 0; k4 < 32; k4++) {
      float w0 = g_w2t[(k4 * 4 + 0) * 64 + o];
      float w1 = g_w2t[(k4 * 4 + 1) * 64 + o];
      float w2 = g_w2t[(k4 * 4 + 2) * 64 + o];
      float w3 = g_w2t[(k4 * 4 + 3) * 64 + o];
      float4 f0 = *(const float4*)(f0p + k4 * 4);
      float4 f1 = *(const float4*)(f1p + k4 * 4);
      a0 = fmaf(w0, f0.x, a0); a0 = fmaf(w1, f0.y, a0);
      a0 = fmaf(w2, f0.z, a0); a0 = fmaf(w3, f0.w, a0);
      a1 = fmaf(w0, f1.x, a1); a1 = fmaf(w1, f1.y, a1);
      a1 = fmaf(w2, f1.z, a1); a1 = fmaf(w3, f1.w, a1);
    }
    float bb = g_b2[o];
    h2[(rg * 2 + 0) * 64 + o] = fmaxf(a0 + bb, 0.f);
    h2[(rg * 2 + 1) * 64 + o] = fmaxf(a1 + bb, 0.f);
  }
  __syncthreads();
  // L3: 64 -> 32 relu
  {
    const int o = tid & 31, rg = tid >> 5;
    const float* fp = h2 + rg * 64;
    float a = 0.f;
    #pragma unroll 4
    for (int k4 = 0; k4 < 16; k4++) {
      float w0 = g_w3t[(k4 * 4 + 0) * 32 + o];
      float w1 = g_w3t[(k4 * 4 + 1) * 32 + o];
      float w2 = g_w3t[(k4 * 4 + 2) * 32 + o];
      float w3 = g_w3t[(k4 * 4 + 3) * 32 + o];
      float4 f0 = *(const float4*)(fp + k4 * 4);
      a = fmaf(w0, f0.x, a); a = fmaf(w1, f0.y, a);
      a = fmaf(w2, f0.z, a); a = fmaf(w3, f0.w, a);
    }
    h3[rg * 32 + o] = fmaxf(a + g_b3[o], 0.f);
  }
  __syncthreads();
  // L4: 32 -> 4 logits
  if (tid < 32) {
    int r = tid >> 2, o = tid & 3;
    const float* hh = h3 + r * 32;
    float a = g_b4[o];
    #pragma unroll
    for (int k = 0; k < 32; k++) a = fmaf(g_w4t[k * 4 + o], hh[k], a);
    lg[tid] = a;
  }
  __syncthreads();
  if (tid < 8) {
    float l0 = lg[tid * 4 + 0], l1 = lg[tid * 4 + 1];
    float l2 = lg[tid * 4 + 2], l3 = lg[tid * 4 + 3];
    float m = fmaxf(fmaxf(l0, l1), fmaxf(l2, l3));
    float e0 = __expf(l0 - m), e1 = __expf(l1 - m);
    float e2 = __expf(l2 - m), e3 = __expf(l3 - m);
    float is = __builtin_amdgcn_rcpf(e0 + e1 + e2 + e3);
    float4 o4; o4.x = e0 * is; o4.y = e1 * is; o4.z = e2 * is; o4.w = e3 * is;
    *(float4*)(out + (size_t)(b0 + tid) * 4) = o4;
  }
}

// ---------------------------------------------------------------------------
extern "C" void kernel_launch(void* const* d_in, const int* in_sizes, int n_in,
                              void* d_out, int out_size, void* d_ws, size_t ws_size,
                              hipStream_t stream) {
  const int*   x     = (const int*)d_in[0];
  const float* emb   = (const float*)d_in[1];
  const float* wih_f = (const float*)d_in[2];
  const float* whh_f = (const float*)d_in[3];
  const float* bih_f = (const float*)d_in[4];
  const float* bhh_f = (const float*)d_in[5];
  const float* wih_r = (const float*)d_in[6];
  const float* whh_r = (const float*)d_in[7];
  const float* bih_r = (const float*)d_in[8];
  const float* bhh_r = (const float*)d_in[9];
  const float* e_w1 = (const float*)d_in[10]; const float* e_b1 = (const float*)d_in[11];
  const float* e_w2 = (const float*)d_in[12]; const float* e_b2 = (const float*)d_in[13];
  const float* l_w1 = (const float*)d_in[14]; const float* l_b1 = (const float*)d_in[15];
  const float* l_w2 = (const float*)d_in[16]; const float* l_b2 = (const float*)d_in[17];
  const float* c_w1 = (const float*)d_in[18]; const float* c_b1 = (const float*)d_in[19];
  const float* c_w2 = (const float*)d_in[20]; const float* c_b2 = (const float*)d_in[21];
  const float* p_w1 = (const float*)d_in[22]; const float* p_b1 = (const float*)d_in[23];
  const float* p_w2 = (const float*)d_in[24]; const float* p_b2 = (const float*)d_in[25];
  const float* x_w1 = (const float*)d_in[26]; const float* x_b1 = (const float*)d_in[27];
  const float* x_w2 = (const float*)d_in[28]; const float* x_b2 = (const float*)d_in[29];
  const float* fp_w = (const float*)d_in[30]; const float* fp_b = (const float*)d_in[31];
  const float* attn_w = (const float*)d_in[32]; const float* attn_b = (const float*)d_in[33];
  const float* out_w = (const float*)d_in[34]; const float* out_b = (const float*)d_in[35];
  const float* g_w1 = (const float*)d_in[36]; const float* g_b1 = (const float*)d_in[37];
  const float* g_w2 = (const float*)d_in[38]; const float* g_b2 = (const float*)d_in[39];
  const float* g_w3 = (const float*)d_in[40]; const float* g_b3 = (const float*)d_in[41];
  const float* g_w4 = (const float*)d_in[42]; const float* g_b4 = (const float*)d_in[43];

  float* ws   = (float*)d_ws;
  float* G_f  = ws;                       // 512*256
  float* G_r  = G_f  + 512 * 256;
  float* hfw  = G_r  + 512 * 256;         // B*64
  float* hrw  = hfw  + BATCH * 64;
  float* entw = hrw  + BATCH * 64;        // B
  float* vlnw = entw + BATCH;
  float* patw = vlnw + BATCH;             // B*6
  float* cpxw = patw + BATCH * 6;         // B*4
  float* Aw   = cpxw + BATCH * 4;         // 128*184
  float* avbw = Aw + 128 * ADJ;           // 128
  float* Bpw  = avbw + 128;               // 184*180
  float* vbw  = Bpw + ADJ * 180;          // 184
  float* C1t  = vbw + ADJ;                // 180*128
  float* c1b  = C1t + 180 * 128;          // 128
  float* g2t  = c1b + 128;                // 128*64
  float* g3t  = g2t + 128 * 64;           // 64*32
  float* g4t  = g3t + 64 * 32;            // 32*4
  float* cw1t = g4t + 32 * 4;             // 512*32
  unsigned short* Wfrag = (unsigned short*)(cw1t + 512 * 32);  // 32768 bf16

  k_prep<<<dim3(465 + BATCH / 4), dim3(256), 0, stream>>>(
      x, emb, wih_f, bih_f, bhh_f, wih_r, bih_r, bhh_r, whh_f, whh_r,
      g_w1, g_b1, out_w, out_b, attn_w, attn_b, fp_w, fp_b,
      g_w2, g_w3, g_w4, c_w1,
      G_f, G_r, Wfrag, Aw, avbw, Bpw, vbw, g2t, g3t, g4t, cw1t,
      entw, vlnw, patw, cpxw);
  k_main<<<dim3(640), dim3(512), 0, stream>>>(
      x, G_f, G_r, Wfrag, Aw, avbw, Bpw, vbw, C1t, c1b, hfw, hrw);
  k_head<<<dim3(BATCH / 8), dim3(256), 0, stream>>>(
      x, hfw, hrw, entw, vlnw, patw, cpxw,
      e_w1, e_b1, e_w2, e_b2, l_w1, l_b1, l_w2, l_b2,
      cw1t, c_b1, c_w2, c_b2, p_w1, p_b1, p_w2, p_b2,
      x_w1, x_b1, x_w2, x_b2, C1t, c1b,
      g2t, g_b2, g3t, g_b3, g4t, g_b4,
      (float*)d_out);
}

// Round 6
// 239.860 us; speedup vs baseline: 1.0379x; 1.0379x over previous
//
#include <hip/hip_runtime.h>

// Problem constants
#define BATCH 4096
#define SEQL  60
#define VOC   512
#define EMBD  128
#define HID   64
#define GATES 256
#define ADJ   184

typedef __attribute__((ext_vector_type(8))) short short8;
typedef __attribute__((ext_vector_type(4))) float f32x4;

// log2(e) and 2*log2(e): gate pre-activations are pre-scaled by these in
// k_prep so the recurrence uses native v_exp_f32 (2^x) with no extra mul.
#define L2E  1.4426950408889634f
#define L2E2 2.8853900817779268f

// G-row stride in LDS staging buffer: 1024 data bytes + 16 pad.
#define GROW 1040

__device__ __forceinline__ float ex2(float x) {
#if __has_builtin(__builtin_amdgcn_exp2f)
  return __builtin_amdgcn_exp2f(x);
#else
  return exp2f(x);
#endif
}
__device__ __forceinline__ unsigned short f2bf_rne(float f) {
  unsigned int u = __float_as_uint(f);
  unsigned int r = (u + 0x7fffu + ((u >> 16) & 1u)) >> 16;
  return (unsigned short)r;
}
__device__ __forceinline__ unsigned int f2bf(float f) {
  // round-half-up: 2 VALU ops (vs 5 for RNE); <=1/2 ulp extra error on |h|<1
  return (__float_as_uint(f) + 0x8000u) >> 16;
}
__device__ __forceinline__ float dot4(float4 a, float4 b, float acc) {
  acc = fmaf(a.x, b.x, acc); acc = fmaf(a.y, b.y, acc);
  acc = fmaf(a.z, b.z, acc); acc = fmaf(a.w, b.w, acc);
  return acc;
}
__device__ __forceinline__ float wsumf(float v) {
  #pragma unroll
  for (int s = 32; s > 0; s >>= 1) v += __shfl_xor(v, s, 64);
  return v;
}
__device__ __forceinline__ int wsumi(int v) {
  #pragma unroll
  for (int s = 32; s > 0; s >>= 1) v += __shfl_xor(v, s, 64);
  return v;
}
__device__ __forceinline__ int wmaxi(int v) {
  #pragma unroll
  for (int s = 32; s > 0; s >>= 1) v = max(v, __shfl_xor(v, s, 64));
  return v;
}
// async global->LDS: lane l writes ldsbase + l*16; global source per-lane.
__device__ __forceinline__ void gload16(const void* g, void* l) {
  __builtin_amdgcn_global_load_lds(
      (const __attribute__((address_space(1))) void*)g,
      (__attribute__((address_space(3))) void*)l, 16, 0, 0);
}

// ---------------------------------------------------------------------------
// k_prep: weight-only prep + per-row sequence stats:
//   [0,128)      G table (interleaved [v][u][4 gates], both dirs), PRESCALED
//                by log2e (i,f,o) / 2*log2e (cell gate)
//   [128,144)    Wfrag: bf16 MFMA A-operands of w_hh, ADJACENT-UNIT packed:
//                fragment (dir,w,m,c): A row rr = du*4 + gate,
//                unit = w*8 + du*2 + m  ->  lane (kg,ln) accumulates the 4
//                gates of units w*8+kg*2 (m=0) and w*8+kg*2+1 (m=1), so the
//                lane's two cells are ADJACENT -> single u32 h write, and
//                its G slice is one contiguous 32B region (C-init fragments).
//   [144,272)    A = g_w1·out_w (+ avb bias fold)
//   [272,456)    B = wv·fp_w    (+ vb bias fold)
//   [456]        transposes g_w2t/g_w3t/g_w4t
//   [457,465)    transpose c_w1 -> c_w1t[512][32], row 0 zeroed
//   [465,1489)   sequence statistics, wave-per-row (4 rows/block)
// ---------------------------------------------------------------------------
__global__ __launch_bounds__(256) void k_prep(
    const int* __restrict__ x,
    const float* __restrict__ emb,
    const float* __restrict__ wih_f, const float* __restrict__ bif, const float* __restrict__ bhf,
    const float* __restrict__ wih_r, const float* __restrict__ bir, const float* __restrict__ bhr,
    const float* __restrict__ whh_f, const float* __restrict__ whh_r,
    const float* __restrict__ g_w1, const float* __restrict__ g_b1,
    const float* __restrict__ out_w, const float* __restrict__ out_b,
    const float* __restrict__ attn_w, const float* __restrict__ attn_b,
    const float* __restrict__ fp_w, const float* __restrict__ fp_b,
    const float* __restrict__ g_w2, const float* __restrict__ g_w3,
    const float* __restrict__ g_w4, const float* __restrict__ c_w1,
    float* __restrict__ G_f, float* __restrict__ G_r,
    unsigned short* __restrict__ Wfrag,
    float* __restrict__ A, float* __restrict__ avb,
    float* __restrict__ Bp, float* __restrict__ vb,
    float* __restrict__ g_w2t, float* __restrict__ g_w3t, float* __restrict__ g_w4t,
    float* __restrict__ c_w1t,
    float* __restrict__ ent_o, float* __restrict__ vlen_o,
    float* __restrict__ pat_o, float* __restrict__ cpx_o) {
  __shared__ unsigned int cnt[4][512];
  __shared__ unsigned short q[4][68];
  const int bid = blockIdx.x;
  const int tid = threadIdx.x;

  if (bid < 128) {
    // ---------------- G table, interleaved [v][u][gg], prescaled ----------------
    const int dir = bid >> 6;
    const int rem = bid & 63;
    const int v0 = (rem >> 2) * 32;
    const int j0 = (rem & 3) * 64;
    const float* W = dir ? wih_r : wih_f;
    const float* bi = dir ? bir : bif;
    const float* bh = dir ? bhr : bhf;
    float* G = dir ? G_r : G_f;
    const int vp = tid >> 4;
    const int jq = tid & 15;
    const int v = v0 + vp * 2;
    const int j = j0 + jq * 4;
    const int gg = j >> 6;
    const int u0 = j & 63;
    const float sc = (gg == 2) ? L2E2 : L2E;

    const float4* E0 = (const float4*)(emb + (size_t)v * 128);
    const float4* E1 = (const float4*)(emb + (size_t)(v + 1) * 128);
    const float4* W0 = (const float4*)(W + (size_t)j * 128);
    const float4* W1 = (const float4*)(W + (size_t)(j + 1) * 128);
    const float4* W2 = (const float4*)(W + (size_t)(j + 2) * 128);
    const float4* W3 = (const float4*)(W + (size_t)(j + 3) * 128);

    float a00 = 0.f, a01 = 0.f, a02 = 0.f, a03 = 0.f;
    float a10 = 0.f, a11 = 0.f, a12 = 0.f, a13 = 0.f;
    #pragma unroll 4
    for (int d4 = 0; d4 < 32; d4++) {
      float4 e0 = E0[d4], e1 = E1[d4];
      float4 w0 = W0[d4], w1 = W1[d4], w2 = W2[d4], w3 = W3[d4];
      a00 = dot4(e0, w0, a00); a01 = dot4(e0, w1, a01);
      a02 = dot4(e0, w2, a02); a03 = dot4(e0, w3, a03);
      a10 = dot4(e1, w0, a10); a11 = dot4(e1, w1, a11);
      a12 = dot4(e1, w2, a12); a13 = dot4(e1, w3, a13);
    }
    float b0v = bi[j] + bh[j], b1v = bi[j + 1] + bh[j + 1];
    float b2v = bi[j + 2] + bh[j + 2], b3v = bi[j + 3] + bh[j + 3];
    float* g0 = G + (size_t)v * 256 + u0 * 4 + gg;
    g0[0]  = (a00 + b0v) * sc; g0[4]  = (a01 + b1v) * sc;
    g0[8]  = (a02 + b2v) * sc; g0[12] = (a03 + b3v) * sc;
    float* g1 = g0 + 256;
    g1[0]  = (a10 + b0v) * sc; g1[4]  = (a11 + b1v) * sc;
    g1[8]  = (a12 + b2v) * sc; g1[12] = (a13 + b3v) * sc;
  } else if (bid < 144) {
    // ---- w_hh bf16 MFMA A-fragments, adjacent-unit packed (prescaled) ----
    const int id = (bid - 128) * 256 + tid;
    const int lane = id & 63;
    const int fc = id >> 6;          // 6 bits: dir|w(3)|m|c
    const int c = fc & 1;
    const int m = (fc >> 1) & 1;
    const int w = (fc >> 2) & 7;
    const int dir = fc >> 5;
    const float* whh = dir ? whh_r : whh_f;
    const int rr = lane & 15;
    const int du = rr >> 2;
    const int gate = rr & 3;
    const int unit = w * 8 + du * 2 + m;
    const float sc = (gate == 2) ? L2E2 : L2E;
    const int n = gate * 64 + unit;
    const int kb = c * 32 + (lane >> 4) * 8;
    unsigned short* o = Wfrag + (size_t)id * 8;
    #pragma unroll
    for (int j = 0; j < 8; j++) o[j] = f2bf_rne(whh[n * 64 + kb + j] * sc);
  } else if (bid < 272) {
    // ---------------- A = g_w1 · out_w  (128 x 184), avb fold ----------------
    const int i = bid - 144;
    const int j = tid;
    const float* g1r = g_w1 + (size_t)i * ADJ;
    if (j < ADJ) {
      float a0 = 0.f, a1 = 0.f, a2 = 0.f, a3 = 0.f;
      for (int k = 0; k < ADJ; k += 4) {
        a0 = fmaf(g1r[k],     out_w[(size_t)(k)     * ADJ + j], a0);
        a1 = fmaf(g1r[k + 1], out_w[(size_t)(k + 1) * ADJ + j], a1);
        a2 = fmaf(g1r[k + 2], out_w[(size_t)(k + 2) * ADJ + j], a2);
        a3 = fmaf(g1r[k + 3], out_w[(size_t)(k + 3) * ADJ + j], a3);
      }
      A[(size_t)i * ADJ + j] = (a0 + a1) + (a2 + a3);
    } else if (j == ADJ) {
      float a0 = 0.f;
      for (int k = 0; k < ADJ; k++) a0 = fmaf(g1r[k], out_b[k], a0);
      avb[i] = a0 + g_b1[i];
    }
  } else if (bid < 456) {
    // ---------------- B = wv · fp_w  (184 x 180), vb fold ----------------
    const int k = bid - 272;
    const int j = tid;
    const float* wvr = attn_w + (size_t)(2 * ADJ + k) * ADJ;
    if (j < 180) {
      float a0 = 0.f, a1 = 0.f, a2 = 0.f, a3 = 0.f;
      for (int m = 0; m < ADJ; m += 4) {
        a0 = fmaf(wvr[m],     fp_w[(size_t)(m)     * 180 + j], a0);
        a1 = fmaf(wvr[m + 1], fp_w[(size_t)(m + 1) * 180 + j], a1);
        a2 = fmaf(wvr[m + 2], fp_w[(size_t)(m + 2) * 180 + j], a2);
        a3 = fmaf(wvr[m + 3], fp_w[(size_t)(m + 3) * 180 + j], a3);
      }
      Bp[(size_t)k * 180 + j] = (a0 + a1) + (a2 + a3);
    } else if (j == 180) {
      float a0 = 0.f;
      for (int m = 0; m < ADJ; m++) a0 = fmaf(wvr[m], fp_b[m], a0);
      vb[k] = a0 + attn_b[2 * ADJ + k];
    }
  } else if (bid == 456) {
    // ---------------- transposes for the head ----------------
    for (int i = tid; i < 64 * 128; i += 256) {
      int o = i >> 7, k = i & 127;
      g_w2t[k * 64 + o] = g_w2[i];
    }
    for (int i = tid; i < 32 * 64; i += 256) {
      int o = i >> 6, k = i & 63;
      g_w3t[k * 32 + o] = g_w3[i];
    }
    if (tid < 128) {
      int o = tid >> 5, k = tid & 31;
      g_w4t[k * 4 + o] = g_w4[tid];
    }
  } else if (bid < 465) {
    // -------- transpose c_w1 (32x512) -> c_w1t (512x32), row 0 zeroed --------
    const int base = (bid - 457) * 2048;   // 8 blocks x 2048 = 16384
    for (int i = tid; i < 2048; i += 256) {
      int idx = base + i;
      int o = idx >> 9, k = idx & 511;
      c_w1t[k * 32 + o] = k ? c_w1[o * 512 + k] : 0.f;
    }
  } else {
    // ======================= sequence statistics =======================
    const int lane = tid & 63;
    const int wid = tid >> 6;
    const int row = (bid - 465) * 4 + wid;
    unsigned int* cr = cnt[wid];
    unsigned short* qr = q[wid];

    for (int i = lane; i < 512; i += 64) cr[i] = 0u;
    qr[lane] = 0;
    if (lane < 4) qr[64 + lane] = 0;
    int v = (lane < 60) ? x[row * 60 + lane] : 0;
    bool act = (v != 0);
    unsigned long long amask = __ballot(act);
    int n = __popcll(amask);
    __syncthreads();
    if (act) {
      int pos = __popcll(amask & ((1ull << lane) - 1ull));
      qr[pos] = (unsigned short)v;
      atomicAdd(&cr[v], 1u);
    }
    __syncthreads();

    float vlenf = (float)(n >= 1 ? n : 1);
    float inv = 1.f / vlenf;

    float ent = 0.f; int distinct = 0;
    #pragma unroll
    for (int j = 0; j < 8; j++) {
      unsigned int c = cr[lane + j * 64];
      if (c) {
        distinct++;
        float p = (float)c * inv;
        ent -= p * __logf(p + 1e-8f);
      }
    }
    ent = wsumf(ent);
    distinct = wsumi(distinct);

    int a = qr[lane], b = qr[lane + 1], c2 = qr[lane + 2];
    bool v1 = (lane + 1 < n);
    bool v2 = (lane + 2 < n);
    int rep  = __popcll(__ballot(v1 && (a == b)));
    int incs = __popcll(__ballot(v1 && (b > a)));
    int decs = __popcll(__ballot(v1 && (b < a)));
    int per2 = __popcll(__ballot(v2 && (a == c2)));

    int prev = (lane > 0) ? (int)qr[lane - 1] : -1;
    bool isst = (lane < n) && (lane == 0 || a != prev);
    unsigned long long smask = __ballot(isst);
    int len = 0;
    if (isst) {
      unsigned long long hi = (lane < 63) ? (smask >> (lane + 1)) : 0ull;
      int next = hi ? (lane + __ffsll((unsigned long long)hi)) : n;
      len = next - lane;
    }
    int maxrun = wmaxi(len);

    int code = v1 ? (a * VOC + b) : -1;
    int unique = v1 ? 1 : 0;
    #pragma unroll 1
    for (int j = 0; j < 58; j++) {
      int cj = __shfl(code, j, 64);
      if (j < lane && cj == code) unique = 0;
    }
    int dc = __popcll(__ballot(unique != 0));

    int wl = n >> 1; if (wl > 5) wl = 5;
    float local = 0.f;
    if (wl >= 2) {
      bool pv = (lane + wl <= n);
      int u = 0;
      if (pv) {
        int t0 = qr[lane], t1 = qr[lane + 1], t2 = qr[lane + 2];
        int t3 = qr[lane + 3], t4 = qr[lane + 4];
        u = 1;
        u += (t1 != t0);
        if (wl >= 3) u += (int)((t2 != t1) && (t2 != t0));
        if (wl >= 4) u += (int)((t3 != t2) && (t3 != t1) && (t3 != t0));
        if (wl >= 5) u += (int)((t4 != t3) && (t4 != t2) && (t4 != t1) && (t4 != t0));
      }
      int usum = wsumi(u);
      int denw = n - wl + 1; if (denw < 1) denw = 1;
      local = (float)usum / (float)wl / (float)denw;
    }

    float den1 = (float)((n - 1) >= 1 ? (n - 1) : 1);
    float repeat = (float)rep / den1;
    float per = (n >= 4) ? (float)per2 / (float)((n - 2) >= 1 ? (n - 2) : 1) : 0.f;
    float entz = (n > 1) ? ent : 0.f;
    float z = (n > 1) ? 1.f : 0.f;

    if (lane == 0) {
      ent_o[row] = entz;
      vlen_o[row] = (float)n;
      pat_o[row * 6 + 0] = repeat * z;
      pat_o[row * 6 + 1] = (float)incs / den1 * z;
      pat_o[row * 6 + 2] = (float)decs / den1 * z;
      pat_o[row * 6 + 3] = per * z;
      pat_o[row * 6 + 4] = (float)distinct * inv * z;
      pat_o[row * 6 + 5] = (float)maxrun * inv * z;
      cpx_o[row * 4 + 0] = (float)dc / den1 * z;
      cpx_o[row * 4 + 1] = entz / __logf((float)(n >= 2 ? n : 2)) * z;
      cpx_o[row * 4 + 2] = local * z;
      cpx_o[row * 4 + 3] = (1.f - repeat) * z;
    }
  }
}

// ---------------------------------------------------------------------------
// k_main: LSTM recurrence + prep2. 512-thread blocks (8 waves).
//   [0,512)    MFMA LSTM. G rows staged to LDS via global_load_lds (R4 path:
//              contiguous 1KB-row DMA, 16 coalesced lines/instr — faster than
//              per-lane gathers, verified R4 vs R5). Adjacent-unit A-packing:
//              lane owns units uA=w*8+kg*2 and uA+1, so its G slice is one
//              32B region read as the two MFMA C-INIT fragments (gate-add
//              folded into the matrix op), the h hand-off is a single
//              aligned u32 (2xbf16, exact 2-way bank alias = free), and the
//              epilogue is one float2 store.
//   [512,640)  prep2: C1t = (A·B)^T, c1b fold.
// ---------------------------------------------------------------------------
#define LSTM_STEP(T)                                                           \
  {                                                                            \
    if ((T) < 59) {                                                            \
      const int tsn = dir ? (58 - (T)) : ((T) + 1);                            \
      const unsigned int* toks = tokoff + tsn * 16;                            \
      char* gdst = Gm + (((T) + 1) & 1) * (16 * GROW) + r2 * GROW;             \
      gload16(GbC + toks[r2 + 0] + lane16, gdst);                              \
      gload16(GbC + toks[r2 + 1] + lane16, gdst + GROW);                       \
    }                                                                          \
    const unsigned short* hb = hbuf[(T) & 1];                                  \
    short8 hf0 = *(const short8*)(hb + rdoff);                                 \
    short8 hf1 = *(const short8*)(hb + rdoff + 32);                            \
    const char* gbp = Gm + ((T) & 1) * (16 * GROW) + goff;                     \
    f32x4 acc0 = *(const f32x4*)(gbp);                                         \
    f32x4 acc1 = *(const f32x4*)(gbp + 16);                                    \
    acc0 = __builtin_amdgcn_mfma_f32_16x16x32_bf16(bfr[0][0], hf0, acc0, 0, 0, 0); \
    acc1 = __builtin_amdgcn_mfma_f32_16x16x32_bf16(bfr[1][0], hf0, acc1, 0, 0, 0); \
    acc0 = __builtin_amdgcn_mfma_f32_16x16x32_bf16(bfr[0][1], hf1, acc0, 0, 0, 0); \
    acc1 = __builtin_amdgcn_mfma_f32_16x16x32_bf16(bfr[1][1], hf1, acc1, 0, 0, 0); \
    unsigned short* hw = hbuf[((T) + 1) & 1];                                  \
    float h0, h1;                                                              \
    {                                                                          \
      float Ef = ex2(-acc0[1]);                                                \
      float E1 = ex2(-acc0[0]);                                                \
      float E2 = ex2(acc0[2]);                                                 \
      float sf = __builtin_amdgcn_rcpf(1.f + Ef);                              \
      float p  = (E2 - 1.f) * __builtin_amdgcn_rcpf((1.f + E1) * (E2 + 1.f));  \
      float cn = fmaf(sf, cst0, p);                                            \
      cst0 = cn;                                                               \
      float E3 = ex2(-acc0[3]);                                                \
      float E4 = ex2(fminf(L2E2 * cn, 126.f));                                 \
      h0 = (E4 - 1.f) * __builtin_amdgcn_rcpf((1.f + E3) * (E4 + 1.f));        \
    }                                                                          \
    {                                                                          \
      float Ef = ex2(-acc1[1]);                                                \
      float E1 = ex2(-acc1[0]);                                                \
      float E2 = ex2(acc1[2]);                                                 \
      float sf = __builtin_amdgcn_rcpf(1.f + Ef);                              \
      float p  = (E2 - 1.f) * __builtin_amdgcn_rcpf((1.f + E1) * (E2 + 1.f));  \
      float cn = fmaf(sf, cst1, p);                                            \
      cst1 = cn;                                                               \
      float E3 = ex2(-acc1[3]);                                                \
      float E4 = ex2(fminf(L2E2 * cn, 126.f));                                 \
      h1 = (E4 - 1.f) * __builtin_amdgcn_rcpf((1.f + E3) * (E4 + 1.f));        \
    }                                                                          \
    *(unsigned int*)(hw + wr0) = f2bf(h0) | (f2bf(h1) << 16);                  \
    if ((T) == 59) {                                                           \
      float2 o2; o2.x = h0; o2.y = h1;                                         \
      *(float2*)(hop) = o2;                                                    \
    }                                                                          \
    __syncthreads();                                                           \
  }

__global__ __launch_bounds__(512) void k_main(
    const int* __restrict__ x,
    const float* __restrict__ G_f, const float* __restrict__ G_r,
    const unsigned short* __restrict__ Wfrag,
    const float* __restrict__ A, const float* __restrict__ avb,
    const float* __restrict__ Bp, const float* __restrict__ vb,
    float* __restrict__ C1t, float* __restrict__ c1b,
    float* __restrict__ hf_o, float* __restrict__ hr_o) {
  __shared__ __align__(16) char Gm[2 * 16 * GROW];          // 33280 B
  __shared__ __align__(16) unsigned short hbuf[2][16 * 72]; // 4608 B
  __shared__ __align__(16) unsigned int tokoff[60 * 16];    // 3840 B
  const int bid = blockIdx.x;
  const int tid = threadIdx.x;

  if (bid < 512) {
    // ======================= LSTM recurrence =======================
    const int lane = tid & 63;
    const int w = tid >> 6;                      // wave id 0..7
    const int dir = bid >> 8;
    const int blk = bid & 255;
    const int b0 = blk << 4;
    const float* G = dir ? G_r : G_f;
    const char* GbC = (const char*)G;
    float* ho = dir ? hr_o : hf_o;

    for (int i = tid; i < 960; i += 512) {
      int r = i / 60, t = i - r * 60;
      tokoff[t * 16 + r] = ((unsigned int)x[(size_t)(b0 + r) * 60 + t]) << 10;
    }
    for (int i = tid; i < 16 * 72; i += 512) hbuf[0][i] = 0;

    // adjacent-unit A fragments: bfr[m][c]
    short8 bfr[2][2];
    #pragma unroll
    for (int m = 0; m < 2; m++)
      #pragma unroll
      for (int c = 0; c < 2; c++) {
        int idx = (((dir * 8 + w) * 2 + m) * 2 + c) * 64 + lane;
        bfr[m][c] = *(const short8*)(Wfrag + (size_t)idx * 8);
      }

    const int kg = lane >> 4;
    const int ln = lane & 15;                    // batch row within tile
    const int uA = w * 8 + kg * 2;               // cell-0 unit; cell-1 = uA+1
    const int rdoff = ln * 72 + kg * 8;          // h-frag read offset (shorts)
    const int wr0 = ln * 72 + uA;                // h write offset (shorts, u32)
    const int r2 = w * 2;                        // rows this wave stages
    const int lane16 = lane * 16;
    const int goff = ln * GROW + uA * 16;        // lane's 32B G slice in Gm
    float* hop = ho + (size_t)(b0 + ln) * 64 + uA;
    float cst0 = 0.f, cst1 = 0.f;

    __syncthreads();   // tokoff + hbuf[0] visible

    // prologue: stage step-0 G rows into Gm[0]
    {
      const int ts0 = dir ? 59 : 0;
      const unsigned int* toks = tokoff + ts0 * 16;
      char* gdst = Gm + r2 * GROW;
      gload16(GbC + toks[r2 + 0] + lane16, gdst);
      gload16(GbC + toks[r2 + 1] + lane16, gdst + GROW);
    }
    __syncthreads();   // drain prologue stage

    #pragma unroll 1
    for (int tt = 0; tt < 30; tt++) {
      const int t0 = tt * 2, t1 = tt * 2 + 1;
      LSTM_STEP(t0)
      LSTM_STEP(t1)
    }
  } else {
    // ======================= prep2 (head collapse) =======================
    const int i = bid - 512, j = tid;
    const float* Ar = A + (size_t)i * ADJ;
    if (j < 180) {
      float a0 = 0.f, a1 = 0.f, a2 = 0.f, a3 = 0.f;
      for (int k = 0; k < ADJ; k += 4) {
        a0 = fmaf(Ar[k],     Bp[(size_t)(k)     * 180 + j], a0);
        a1 = fmaf(Ar[k + 1], Bp[(size_t)(k + 1) * 180 + j], a1);
        a2 = fmaf(Ar[k + 2], Bp[(size_t)(k + 2) * 180 + j], a2);
        a3 = fmaf(Ar[k + 3], Bp[(size_t)(k + 3) * 180 + j], a3);
      }
      C1t[(size_t)j * 128 + i] = (a0 + a1) + (a2 + a3);
    } else if (j == 180) {
      float a0 = 0.f;
      for (int k = 0; k < ADJ; k++) a0 = fmaf(Ar[k], vb[k], a0);
      c1b[i] = a0 + avb[i];
    }
  }
}

// ---------------------------------------------------------------------------
// k_head: feature assembly + collapsed head. c-MLP L1 is a sparse gather:
// counts·W == sum_t W[x_t] (row 0 of c_w1t zeroed), 60 gathers vs 512 streams.
// 512 blocks x 256 threads, 8 rows/block.
// ---------------------------------------------------------------------------
#define FSTR 192

__global__ __launch_bounds__(256) void k_head(
    const int* __restrict__ x,
    const float* __restrict__ hf, const float* __restrict__ hr,
    const float* __restrict__ ent, const float* __restrict__ vlen,
    const float* __restrict__ pat, const float* __restrict__ cpx,
    const float* __restrict__ e_w1, const float* __restrict__ e_b1,
    const float* __restrict__ e_w2, const float* __restrict__ e_b2,
    const float* __restrict__ l_w1, const float* __restrict__ l_b1,
    const float* __restrict__ l_w2, const float* __restrict__ l_b2,
    const float* __restrict__ c_w1t, const float* __restrict__ c_b1,
    const float* __restrict__ c_w2, const float* __restrict__ c_b2,
    const float* __restrict__ p_w1, const float* __restrict__ p_b1,
    const float* __restrict__ p_w2, const float* __restrict__ p_b2,
    const float* __restrict__ x_w1, const float* __restrict__ x_b1,
    const float* __restrict__ x_w2, const float* __restrict__ x_b2,
    const float* __restrict__ C1t, const float* __restrict__ c1b,
    const float* __restrict__ g_w2t, const float* __restrict__ g_b2,
    const float* __restrict__ g_w3t, const float* __restrict__ g_b3,
    const float* __restrict__ g_w4t, const float* __restrict__ g_b4,
    float* __restrict__ out) {
  __shared__ float feat[8 * FSTR];
  __shared__ unsigned short tk[8 * 64];
  __shared__ float h1[8 * 128];
  __shared__ float h2[8 * 64];
  __shared__ float h3[8 * 32];
  __shared__ float h1c[8 * 33];
  __shared__ float lg[32];
  const int tid = threadIdx.x;
  const int b0 = blockIdx.x * 8;

  // h_f / h_r -> feat[0:128)
  if (tid < 128) {
    int r = tid >> 4, c = tid & 15;
    float4 vv = ((const float4*)(hf + (size_t)(b0 + r) * 64))[c];
    *(float4*)(feat + r * FSTR + c * 4) = vv;
  } else {
    int t = tid - 128;
    int r = t >> 4, c = t & 15;
    float4 vv = ((const float4*)(hr + (size_t)(b0 + r) * 64))[c];
    *(float4*)(feat + r * FSTR + 64 + c * 4) = vv;
  }
  // tokens -> LDS (8 rows x 60)
  for (int i = tid; i < 480; i += 256) {
    int r = i / 60, t = i - r * 60;
    tk[r * 64 + t] = (unsigned short)x[(size_t)(b0 + r) * 60 + t];
  }
  __syncthreads();
  // c-MLP layer 1 sparse: o = tid&31 (coalesced gather), r = tid>>5
  {
    int o = tid & 31, r = tid >> 5;
    const unsigned short* tkr = tk + r * 64;
    float a0 = 0.f, a1 = 0.f, a2 = 0.f, a3 = 0.f;
    #pragma unroll 5
    for (int t = 0; t < 60; t += 4) {
      int t0 = tkr[t], t1 = tkr[t + 1], t2 = tkr[t + 2], t3 = tkr[t + 3];
      a0 += c_w1t[t0 * 32 + o];
      a1 += c_w1t[t1 * 32 + o];
      a2 += c_w1t[t2 * 32 + o];
      a3 += c_w1t[t3 * 32 + o];
    }
    float invv = __builtin_amdgcn_rcpf(fmaxf(vlen[b0 + r], 1.f));
    h1c[r * 33 + o] = fmaxf(((a0 + a1) + (a2 + a3)) * invv + c_b1[o], 0.f);
  }
  __syncthreads();
  // small MLPs (threads 0..31) + c-MLP layer 2 (threads 64..191)
  if (tid < 32) {
    const int m = tid & 3, r = tid >> 2, b = b0 + r;
    float tt[24];
    if (m == 0) {
      float ein = ent[b] * 0.25f;
      #pragma unroll
      for (int o = 0; o < 16; o++) tt[o] = fmaxf(e_w1[o] * ein + e_b1[o], 0.f);
      #pragma unroll
      for (int o = 0; o < 8; o++) {
        float a = e_b2[o];
        #pragma unroll
        for (int k = 0; k < 16; k++) a = fmaf(e_w2[o * 16 + k], tt[k], a);
        feat[r * FSTR + 128 + o] = a;
      }
    } else if (m == 1) {
      float lin = vlen[b] * (1.f / 60.f);
      #pragma unroll
      for (int o = 0; o < 16; o++) tt[o] = fmaxf(l_w1[o] * lin + l_b1[o], 0.f);
      #pragma unroll
      for (int o = 0; o < 8; o++) {
        float a = l_b2[o];
        #pragma unroll
        for (int k = 0; k < 16; k++) a = fmaf(l_w2[o * 16 + k], tt[k], a);
        feat[r * FSTR + 136 + o] = a;
      }
    } else if (m == 2) {
      float pin[6];
      #pragma unroll
      for (int k = 0; k < 6; k++) pin[k] = pat[b * 6 + k];
      #pragma unroll
      for (int o = 0; o < 24; o++) {
        float a = p_b1[o];
        #pragma unroll
        for (int k = 0; k < 6; k++) a = fmaf(p_w1[o * 6 + k], pin[k], a);
        tt[o] = fmaxf(a, 0.f);
      }
      #pragma unroll
      for (int o = 0; o < 12; o++) {
        float a = p_b2[o];
        #pragma unroll
        for (int k = 0; k < 24; k++) a = fmaf(p_w2[o * 24 + k], tt[k], a);
        feat[r * FSTR + 160 + o] = a;
      }
    } else {
      float xin[4];
      #pragma unroll
      for (int k = 0; k < 4; k++) xin[k] = cpx[b * 4 + k];
      #pragma unroll
      for (int o = 0; o < 16; o++) {
        float a = x_b1[o];
        #pragma unroll
        for (int k = 0; k < 4; k++) a = fmaf(x_w1[o * 4 + k], xin[k], a);
        tt[o] = fmaxf(a, 0.f);
      }
      #pragma unroll
      for (int o = 0; o < 8; o++) {
        float a = x_b2[o];
        #pragma unroll
        for (int k = 0; k < 16; k++) a = fmaf(x_w2[o * 16 + k], tt[k], a);
        feat[r * FSTR + 172 + o] = a;
      }
    }
  } else if (tid >= 64 && tid < 192) {
    int t = tid - 64;
    int r = t >> 4, o = t & 15;
    float a = c_b2[o];
    const float* hh = h1c + r * 33;
    #pragma unroll
    for (int k = 0; k < 32; k++) a = fmaf(c_w2[o * 32 + k], hh[k], a);
    feat[r * FSTR + 144 + o] = a;
  }
  __syncthreads();

  // L1: 180 -> 128 relu. C1t lane-coalesced, feat b128 broadcasts.
  {
    const int o = tid & 127, rg = tid >> 7;
    const float* f0p = feat + (rg * 4 + 0) * FSTR;
    const float* f1p = feat + (rg * 4 + 1) * FSTR;
    const float* f2p = feat + (rg * 4 + 2) * FSTR;
    const float* f3p = feat + (rg * 4 + 3) * FSTR;
    float a0 = 0.f, a1 = 0.f, a2 = 0.f, a3 = 0.f;
    #pragma unroll 3
    for (int k4 = 0; k4 < 45; k4++) {
      float w0 = C1t[(size_t)(k4 * 4 + 0) * 128 + o];
      float w1 = C1t[(size_t)(k4 * 4 + 1) * 128 + o];
      float w2 = C1t[(size_t)(k4 * 4 + 2) * 128 + o];
      float w3 = C1t[(size_t)(k4 * 4 + 3) * 128 + o];
      float4 f0 = *(const float4*)(f0p + k4 * 4);
      float4 f1 = *(const float4*)(f1p + k4 * 4);
      float4 f2 = *(const float4*)(f2p + k4 * 4);
      float4 f3 = *(const float4*)(f3p + k4 * 4);
      a0 = fmaf(w0, f0.x, a0); a0 = fmaf(w1, f0.y, a0);
      a0 = fmaf(w2, f0.z, a0); a0 = fmaf(w3, f0.w, a0);
      a1 = fmaf(w0, f1.x, a1); a1 = fmaf(w1, f1.y, a1);
      a1 = fmaf(w2, f1.z, a1); a1 = fmaf(w3, f1.w, a1);
      a2 = fmaf(w0, f2.x, a2); a2 = fmaf(w1, f2.y, a2);
      a2 = fmaf(w2, f2.z, a2); a2 = fmaf(w3, f2.w, a2);
      a3 = fmaf(w0, f3.x, a3); a3 = fmaf(w1, f3.y, a3);
      a3 = fmaf(w2, f3.z, a3); a3 = fmaf(w3, f3.w, a3);
    }
    float bb = c1b[o];
    h1[(rg * 4 + 0) * 128 + o] = fmaxf(a0 + bb, 0.f);
    h1[(rg * 4 + 1) * 128 + o] = fmaxf(a1 + bb, 0.f);
    h1[(rg * 4 + 2) * 128 + o] = fmaxf(a2 + bb, 0.f);
    h1[(rg * 4 + 3) * 128 + o] = fmaxf(a3 + bb, 0.f);
  }
  __syncthreads();
  // L2: 128 -> 64 relu
  {
    const int o = tid & 63, rg = tid >> 6;
    const float* f0p = h1 + (rg * 2 + 0) * 128;
    const float* f1p = h1 + (rg * 2 + 1) * 128;
    float a0 = 0.f, a1 = 0.f;
    #pragma unroll 4
    for (int k4 = 0; k4 < 32; k4++) {
      float w0 = g_w2t[(k4 * 4 + 0) * 64 + o];
      float w1 = g_w2t[(k4 * 4 + 1) * 64 + o];
      float w2 = g_w2t[(k4 * 4 + 2) * 64 + o];
      float w3 = g_w2t[(k4 * 4 + 3) * 64 + o];
      float4 f0 = *(const float4*)(f0p + k4 * 4);
      float4 f1 = *(const float4*)(f1p + k4 * 4);
      a0 = fmaf(w0, f0.x, a0); a0 = fmaf(w1, f0.y, a0);
      a0 = fmaf(w2, f0.z, a0); a0 = fmaf(w3, f0.w, a0);
      a1 = fmaf(w0, f1.x, a1); a1 = fmaf(w1, f1.y, a1);
      a1 = fmaf(w2, f1.z, a1); a1 = fmaf(w3, f1.w, a1);
    }
    float bb = g_b2[o];
    h2[(rg * 2 + 0) * 64 + o] = fmaxf(a0 + bb, 0.f);
    h2[(rg * 2 + 1) * 64 + o] = fmaxf(a1 + bb, 0.f);
  }
  __syncthreads();
  // L3: 64 -> 32 relu
  {
    const int o = tid & 31, rg = tid >> 5;
    const float* fp = h2 + rg * 64;
    float a = 0.f;
    #pragma unroll 4
    for (int k4 = 0; k4 < 16; k4++) {
      float w0 = g_w3t[(k4 * 4 + 0) * 32 + o];
      float w1 = g_w3t[(k4 * 4 + 1) * 32 + o];
      float w2 = g_w3t[(k4 * 4 + 2) * 32 + o];
      float w3 = g_w3t[(k4 * 4 + 3) * 32 + o];
      float4 f0 = *(const float4*)(fp + k4 * 4);
      a = fmaf(w0, f0.x, a); a = fmaf(w1, f0.y, a);
      a = fmaf(w2, f0.z, a); a = fmaf(w3, f0.w, a);
    }
    h3[rg * 32 + o] = fmaxf(a + g_b3[o], 0.f);
  }
  __syncthreads();
  // L4: 32 -> 4 logits
  if (tid < 32) {
    int r = tid >> 2, o = tid & 3;
    const float* hh = h3 + r * 32;
    float a = g_b4[o];
    #pragma unroll
    for (int k = 0; k < 32; k++) a = fmaf(g_w4t[k * 4 + o], hh[k], a);
    lg[tid] = a;
  }
  __syncthreads();
  if (tid < 8) {
    float l0 = lg[tid * 4 + 0], l1 = lg[tid * 4 + 1];
    float l2 = lg[tid * 4 + 2], l3 = lg[tid * 4 + 3];
    float m = fmaxf(fmaxf(l0, l1), fmaxf(l2, l3));
    float e0 = __expf(l0 - m), e1 = __expf(l1 - m);
    float e2 = __expf(l2 - m), e3 = __expf(l3 - m);
    float is = __builtin_amdgcn_rcpf(e0 + e1 + e2 + e3);
    float4 o4; o4.x = e0 * is; o4.y = e1 * is; o4.z = e2 * is; o4.w = e3 * is;
    *(float4*)(out + (size_t)(b0 + tid) * 4) = o4;
  }
}

// ---------------------------------------------------------------------------
extern "C" void kernel_launch(void* const* d_in, const int* in_sizes, int n_in,
                              void* d_out, int out_size, void* d_ws, size_t ws_size,
                              hipStream_t stream) {
  const int*   x     = (const int*)d_in[0];
  const float* emb   = (const float*)d_in[1];
  const float* wih_f = (const float*)d_in[2];
  const float* whh_f = (const float*)d_in[3];
  const float* bih_f = (const float*)d_in[4];
  const float* bhh_f = (const float*)d_in[5];
  const float* wih_r = (const float*)d_in[6];
  const float* whh_r = (const float*)d_in[7];
  const float* bih_r = (const float*)d_in[8];
  const float* bhh_r = (const float*)d_in[9];
  const float* e_w1 = (const float*)d_in[10]; const float* e_b1 = (const float*)d_in[11];
  const float* e_w2 = (const float*)d_in[12]; const float* e_b2 = (const float*)d_in[13];
  const float* l_w1 = (const float*)d_in[14]; const float* l_b1 = (const float*)d_in[15];
  const float* l_w2 = (const float*)d_in[16]; const float* l_b2 = (const float*)d_in[17];
  const float* c_w1 = (const float*)d_in[18]; const float* c_b1 = (const float*)d_in[19];
  const float* c_w2 = (const float*)d_in[20]; const float* c_b2 = (const float*)d_in[21];
  const float* p_w1 = (const float*)d_in[22]; const float* p_b1 = (const float*)d_in[23];
  const float* p_w2 = (const float*)d_in[24]; const float* p_b2 = (const float*)d_in[25];
  const float* x_w1 = (const float*)d_in[26]; const float* x_b1 = (const float*)d_in[27];
  const float* x_w2 = (const float*)d_in[28]; const float* x_b2 = (const float*)d_in[29];
  const float* fp_w = (const float*)d_in[30]; const float* fp_b = (const float*)d_in[31];
  const float* attn_w = (const float*)d_in[32]; const float* attn_b = (const float*)d_in[33];
  const float* out_w = (const float*)d_in[34]; const float* out_b = (const float*)d_in[35];
  const float* g_w1 = (const float*)d_in[36]; const float* g_b1 = (const float*)d_in[37];
  const float* g_w2 = (const float*)d_in[38]; const float* g_b2 = (const float*)d_in[39];
  const float* g_w3 = (const float*)d_in[40]; const float* g_b3 = (const float*)d_in[41];
  const float* g_w4 = (const float*)d_in[42]; const float* g_b4 = (const float*)d_in[43];

  float* ws   = (float*)d_ws;
  float* G_f  = ws;                       // 512*256
  float* G_r  = G_f  + 512 * 256;
  float* hfw  = G_r  + 512 * 256;         // B*64
  float* hrw  = hfw  + BATCH * 64;
  float* entw = hrw  + BATCH * 64;        // B
  float* vlnw = entw + BATCH;
  float* patw = vlnw + BATCH;             // B*6
  float* cpxw = patw + BATCH * 6;         // B*4
  float* Aw   = cpxw + BATCH * 4;         // 128*184
  float* avbw = Aw + 128 * ADJ;           // 128
  float* Bpw  = avbw + 128;               // 184*180
  float* vbw  = Bpw + ADJ * 180;          // 184
  float* C1t  = vbw + ADJ;                // 180*128
  float* c1b  = C1t + 180 * 128;          // 128
  float* g2t  = c1b + 128;                // 128*64
  float* g3t  = g2t + 128 * 64;           // 64*32
  float* g4t  = g3t + 64 * 32;            // 32*4
  float* cw1t = g4t + 32 * 4;             // 512*32
  unsigned short* Wfrag = (unsigned short*)(cw1t + 512 * 32);  // 32768 bf16

  k_prep<<<dim3(465 + BATCH / 4), dim3(256), 0, stream>>>(
      x, emb, wih_f, bih_f, bhh_f, wih_r, bih_r, bhh_r, whh_f, whh_r,
      g_w1, g_b1, out_w, out_b, attn_w, attn_b, fp_w, fp_b,
      g_w2, g_w3, g_w4, c_w1,
      G_f, G_r, Wfrag, Aw, avbw, Bpw, vbw, g2t, g3t, g4t, cw1t,
      entw, vlnw, patw, cpxw);
  k_main<<<dim3(640), dim3(512), 0, stream>>>(
      x, G_f, G_r, Wfrag, Aw, avbw, Bpw, vbw, C1t, c1b, hfw, hrw);
  k_head<<<dim3(BATCH / 8), dim3(256), 0, stream>>>(
      x, hfw, hrw, entw, vlnw, patw, cpxw,
      e_w1, e_b1, e_w2, e_b2, l_w1, l_b1, l_w2, l_b2,
      cw1t, c_b1, c_w2, c_b2, p_w1, p_b1, p_w2, p_b2,
      x_w1, x_b1, x_w2, x_b2, C1t, c1b,
      g2t, g_b2, g3t, g_b3, g4t, g_b4,
      (float*)d_out);
}

// Round 7
// 231.028 us; speedup vs baseline: 1.0776x; 1.0382x over previous
//
#include <hip/hip_runtime.h>

// Problem constants
#define BATCH 4096
#define SEQL  60
#define VOC   512
#define EMBD  128
#define HID   64
#define GATES 256
#define ADJ   184

typedef __attribute__((ext_vector_type(8))) short short8;
typedef __attribute__((ext_vector_type(4))) float f32x4;
typedef __attribute__((ext_vector_type(8))) _Float16 h16x8;

// log2(e) and 2*log2(e): gate pre-activations are pre-scaled by these in
// k_prep so the recurrence uses native v_exp_f32 (2^x) with no extra mul.
#define L2E  1.4426950408889634f
#define L2E2 2.8853900817779268f

__device__ __forceinline__ float ex2(float x) {
#if __has_builtin(__builtin_amdgcn_exp2f)
  return __builtin_amdgcn_exp2f(x);
#else
  return exp2f(x);
#endif
}
__device__ __forceinline__ unsigned short f2bf_rne(float f) {
  unsigned int u = __float_as_uint(f);
  unsigned int r = (u + 0x7fffu + ((u >> 16) & 1u)) >> 16;
  return (unsigned short)r;
}
__device__ __forceinline__ float dot4(float4 a, float4 b, float acc) {
  acc = fmaf(a.x, b.x, acc); acc = fmaf(a.y, b.y, acc);
  acc = fmaf(a.z, b.z, acc); acc = fmaf(a.w, b.w, acc);
  return acc;
}
__device__ __forceinline__ float wsumf(float v) {
  #pragma unroll
  for (int s = 32; s > 0; s >>= 1) v += __shfl_xor(v, s, 64);
  return v;
}
__device__ __forceinline__ int wsumi(int v) {
  #pragma unroll
  for (int s = 32; s > 0; s >>= 1) v += __shfl_xor(v, s, 64);
  return v;
}
__device__ __forceinline__ int wmaxi(int v) {
  #pragma unroll
  for (int s = 32; s > 0; s >>= 1) v = max(v, __shfl_xor(v, s, 64));
  return v;
}
// async global->LDS: lane l writes ldsbase + l*16; global source per-lane.
__device__ __forceinline__ void gload16(const void* g, void* l) {
  __builtin_amdgcn_global_load_lds(
      (const __attribute__((address_space(1))) void*)g,
      (__attribute__((address_space(3))) void*)l, 16, 0, 0);
}

// ---------------------------------------------------------------------------
// k_prep: weight-only prep + per-row sequence stats:
//   [0,128)      G table in FP16 ([v][u][4 gates], both dirs, 512B/token),
//                PRESCALED by log2e (i,f,o) / 2*log2e (cell gate).
//                fp16: pre-acts are O(0.1), rel err 5e-4 -- harmless, and it
//                halves the LSTM's stage+read traffic end to end.
//   [128,144)    Wfrag: bf16 MFMA A-operands of w_hh, ADJACENT-UNIT packed:
//                A row rr = du*4 + gate, unit = w*8 + du*2 + m -> lane's two
//                cells are adjacent units (single u32 h write, 16B G slice).
//   [144,272)    A = g_w1·out_w (+ avb bias fold)
//   [272,456)    B = wv·fp_w    (+ vb bias fold)
//   [456]        transposes g_w2t/g_w3t/g_w4t
//   [457,465)    transpose c_w1 -> c_w1t[512][32], row 0 zeroed
//   [465,1489)   sequence statistics, wave-per-row (4 rows/block)
// ---------------------------------------------------------------------------
__global__ __launch_bounds__(256) void k_prep(
    const int* __restrict__ x,
    const float* __restrict__ emb,
    const float* __restrict__ wih_f, const float* __restrict__ bif, const float* __restrict__ bhf,
    const float* __restrict__ wih_r, const float* __restrict__ bir, const float* __restrict__ bhr,
    const float* __restrict__ whh_f, const float* __restrict__ whh_r,
    const float* __restrict__ g_w1, const float* __restrict__ g_b1,
    const float* __restrict__ out_w, const float* __restrict__ out_b,
    const float* __restrict__ attn_w, const float* __restrict__ attn_b,
    const float* __restrict__ fp_w, const float* __restrict__ fp_b,
    const float* __restrict__ g_w2, const float* __restrict__ g_w3,
    const float* __restrict__ g_w4, const float* __restrict__ c_w1,
    float* __restrict__ G_f, float* __restrict__ G_r,
    unsigned short* __restrict__ Wfrag,
    float* __restrict__ A, float* __restrict__ avb,
    float* __restrict__ Bp, float* __restrict__ vb,
    float* __restrict__ g_w2t, float* __restrict__ g_w3t, float* __restrict__ g_w4t,
    float* __restrict__ c_w1t,
    float* __restrict__ ent_o, float* __restrict__ vlen_o,
    float* __restrict__ pat_o, float* __restrict__ cpx_o) {
  __shared__ unsigned int cnt[4][512];
  __shared__ unsigned short q[4][68];
  const int bid = blockIdx.x;
  const int tid = threadIdx.x;

  if (bid < 128) {
    // ---------------- G table (fp16), [v][u][gg], prescaled ----------------
    const int dir = bid >> 6;
    const int rem = bid & 63;
    const int v0 = (rem >> 2) * 32;
    const int j0 = (rem & 3) * 64;
    const float* W = dir ? wih_r : wih_f;
    const float* bi = dir ? bir : bif;
    const float* bh = dir ? bhr : bhf;
    _Float16* Gh = (_Float16*)(dir ? G_r : G_f);
    const int vp = tid >> 4;
    const int jq = tid & 15;
    const int v = v0 + vp * 2;
    const int j = j0 + jq * 4;
    const int gg = j >> 6;
    const int u0 = j & 63;
    const float sc = (gg == 2) ? L2E2 : L2E;

    const float4* E0 = (const float4*)(emb + (size_t)v * 128);
    const float4* E1 = (const float4*)(emb + (size_t)(v + 1) * 128);
    const float4* W0 = (const float4*)(W + (size_t)j * 128);
    const float4* W1 = (const float4*)(W + (size_t)(j + 1) * 128);
    const float4* W2 = (const float4*)(W + (size_t)(j + 2) * 128);
    const float4* W3 = (const float4*)(W + (size_t)(j + 3) * 128);

    float a00 = 0.f, a01 = 0.f, a02 = 0.f, a03 = 0.f;
    float a10 = 0.f, a11 = 0.f, a12 = 0.f, a13 = 0.f;
    #pragma unroll 4
    for (int d4 = 0; d4 < 32; d4++) {
      float4 e0 = E0[d4], e1 = E1[d4];
      float4 w0 = W0[d4], w1 = W1[d4], w2 = W2[d4], w3 = W3[d4];
      a00 = dot4(e0, w0, a00); a01 = dot4(e0, w1, a01);
      a02 = dot4(e0, w2, a02); a03 = dot4(e0, w3, a03);
      a10 = dot4(e1, w0, a10); a11 = dot4(e1, w1, a11);
      a12 = dot4(e1, w2, a12); a13 = dot4(e1, w3, a13);
    }
    float b0v = bi[j] + bh[j], b1v = bi[j + 1] + bh[j + 1];
    float b2v = bi[j + 2] + bh[j + 2], b3v = bi[j + 3] + bh[j + 3];
    _Float16* g0 = Gh + (size_t)v * 256 + u0 * 4 + gg;
    g0[0]  = (_Float16)((a00 + b0v) * sc); g0[4]  = (_Float16)((a01 + b1v) * sc);
    g0[8]  = (_Float16)((a02 + b2v) * sc); g0[12] = (_Float16)((a03 + b3v) * sc);
    _Float16* g1 = g0 + 256;
    g1[0]  = (_Float16)((a10 + b0v) * sc); g1[4]  = (_Float16)((a11 + b1v) * sc);
    g1[8]  = (_Float16)((a12 + b2v) * sc); g1[12] = (_Float16)((a13 + b3v) * sc);
  } else if (bid < 144) {
    // ---- w_hh bf16 MFMA A-fragments, adjacent-unit packed (prescaled) ----
    const int id = (bid - 128) * 256 + tid;
    const int lane = id & 63;
    const int fc = id >> 6;          // 6 bits: dir|w(3)|m|c
    const int c = fc & 1;
    const int m = (fc >> 1) & 1;
    const int w = (fc >> 2) & 7;
    const int dir = fc >> 5;
    const float* whh = dir ? whh_r : whh_f;
    const int rr = lane & 15;
    const int du = rr >> 2;
    const int gate = rr & 3;
    const int unit = w * 8 + du * 2 + m;
    const float sc = (gate == 2) ? L2E2 : L2E;
    const int n = gate * 64 + unit;
    const int kb = c * 32 + (lane >> 4) * 8;
    unsigned short* o = Wfrag + (size_t)id * 8;
    #pragma unroll
    for (int j = 0; j < 8; j++) o[j] = f2bf_rne(whh[n * 64 + kb + j] * sc);
  } else if (bid < 272) {
    // ---------------- A = g_w1 · out_w  (128 x 184), avb fold ----------------
    const int i = bid - 144;
    const int j = tid;
    const float* g1r = g_w1 + (size_t)i * ADJ;
    if (j < ADJ) {
      float a0 = 0.f, a1 = 0.f, a2 = 0.f, a3 = 0.f;
      for (int k = 0; k < ADJ; k += 4) {
        a0 = fmaf(g1r[k],     out_w[(size_t)(k)     * ADJ + j], a0);
        a1 = fmaf(g1r[k + 1], out_w[(size_t)(k + 1) * ADJ + j], a1);
        a2 = fmaf(g1r[k + 2], out_w[(size_t)(k + 2) * ADJ + j], a2);
        a3 = fmaf(g1r[k + 3], out_w[(size_t)(k + 3) * ADJ + j], a3);
      }
      A[(size_t)i * ADJ + j] = (a0 + a1) + (a2 + a3);
    } else if (j == ADJ) {
      float a0 = 0.f;
      for (int k = 0; k < ADJ; k++) a0 = fmaf(g1r[k], out_b[k], a0);
      avb[i] = a0 + g_b1[i];
    }
  } else if (bid < 456) {
    // ---------------- B = wv · fp_w  (184 x 180), vb fold ----------------
    const int k = bid - 272;
    const int j = tid;
    const float* wvr = attn_w + (size_t)(2 * ADJ + k) * ADJ;
    if (j < 180) {
      float a0 = 0.f, a1 = 0.f, a2 = 0.f, a3 = 0.f;
      for (int m = 0; m < ADJ; m += 4) {
        a0 = fmaf(wvr[m],     fp_w[(size_t)(m)     * 180 + j], a0);
        a1 = fmaf(wvr[m + 1], fp_w[(size_t)(m + 1) * 180 + j], a1);
        a2 = fmaf(wvr[m + 2], fp_w[(size_t)(m + 2) * 180 + j], a2);
        a3 = fmaf(wvr[m + 3], fp_w[(size_t)(m + 3) * 180 + j], a3);
      }
      Bp[(size_t)k * 180 + j] = (a0 + a1) + (a2 + a3);
    } else if (j == 180) {
      float a0 = 0.f;
      for (int m = 0; m < ADJ; m++) a0 = fmaf(wvr[m], fp_b[m], a0);
      vb[k] = a0 + attn_b[2 * ADJ + k];
    }
  } else if (bid == 456) {
    // ---------------- transposes for the head ----------------
    for (int i = tid; i < 64 * 128; i += 256) {
      int o = i >> 7, k = i & 127;
      g_w2t[k * 64 + o] = g_w2[i];
    }
    for (int i = tid; i < 32 * 64; i += 256) {
      int o = i >> 6, k = i & 63;
      g_w3t[k * 32 + o] = g_w3[i];
    }
    if (tid < 128) {
      int o = tid >> 5, k = tid & 31;
      g_w4t[k * 4 + o] = g_w4[tid];
    }
  } else if (bid < 465) {
    // -------- transpose c_w1 (32x512) -> c_w1t (512x32), row 0 zeroed --------
    const int base = (bid - 457) * 2048;   // 8 blocks x 2048 = 16384
    for (int i = tid; i < 2048; i += 256) {
      int idx = base + i;
      int o = idx >> 9, k = idx & 511;
      c_w1t[k * 32 + o] = k ? c_w1[o * 512 + k] : 0.f;
    }
  } else {
    // ======================= sequence statistics =======================
    const int lane = tid & 63;
    const int wid = tid >> 6;
    const int row = (bid - 465) * 4 + wid;
    unsigned int* cr = cnt[wid];
    unsigned short* qr = q[wid];

    for (int i = lane; i < 512; i += 64) cr[i] = 0u;
    qr[lane] = 0;
    if (lane < 4) qr[64 + lane] = 0;
    int v = (lane < 60) ? x[row * 60 + lane] : 0;
    bool act = (v != 0);
    unsigned long long amask = __ballot(act);
    int n = __popcll(amask);
    __syncthreads();
    if (act) {
      int pos = __popcll(amask & ((1ull << lane) - 1ull));
      qr[pos] = (unsigned short)v;
      atomicAdd(&cr[v], 1u);
    }
    __syncthreads();

    float vlenf = (float)(n >= 1 ? n : 1);
    float inv = 1.f / vlenf;

    float ent = 0.f; int distinct = 0;
    #pragma unroll
    for (int j = 0; j < 8; j++) {
      unsigned int c = cr[lane + j * 64];
      if (c) {
        distinct++;
        float p = (float)c * inv;
        ent -= p * __logf(p + 1e-8f);
      }
    }
    ent = wsumf(ent);
    distinct = wsumi(distinct);

    int a = qr[lane], b = qr[lane + 1], c2 = qr[lane + 2];
    bool v1 = (lane + 1 < n);
    bool v2 = (lane + 2 < n);
    int rep  = __popcll(__ballot(v1 && (a == b)));
    int incs = __popcll(__ballot(v1 && (b > a)));
    int decs = __popcll(__ballot(v1 && (b < a)));
    int per2 = __popcll(__ballot(v2 && (a == c2)));

    int prev = (lane > 0) ? (int)qr[lane - 1] : -1;
    bool isst = (lane < n) && (lane == 0 || a != prev);
    unsigned long long smask = __ballot(isst);
    int len = 0;
    if (isst) {
      unsigned long long hi = (lane < 63) ? (smask >> (lane + 1)) : 0ull;
      int next = hi ? (lane + __ffsll((unsigned long long)hi)) : n;
      len = next - lane;
    }
    int maxrun = wmaxi(len);

    int code = v1 ? (a * VOC + b) : -1;
    int unique = v1 ? 1 : 0;
    #pragma unroll 1
    for (int j = 0; j < 58; j++) {
      int cj = __shfl(code, j, 64);
      if (j < lane && cj == code) unique = 0;
    }
    int dc = __popcll(__ballot(unique != 0));

    int wl = n >> 1; if (wl > 5) wl = 5;
    float local = 0.f;
    if (wl >= 2) {
      bool pv = (lane + wl <= n);
      int u = 0;
      if (pv) {
        int t0 = qr[lane], t1 = qr[lane + 1], t2 = qr[lane + 2];
        int t3 = qr[lane + 3], t4 = qr[lane + 4];
        u = 1;
        u += (t1 != t0);
        if (wl >= 3) u += (int)((t2 != t1) && (t2 != t0));
        if (wl >= 4) u += (int)((t3 != t2) && (t3 != t1) && (t3 != t0));
        if (wl >= 5) u += (int)((t4 != t3) && (t4 != t2) && (t4 != t1) && (t4 != t0));
      }
      int usum = wsumi(u);
      int denw = n - wl + 1; if (denw < 1) denw = 1;
      local = (float)usum / (float)wl / (float)denw;
    }

    float den1 = (float)((n - 1) >= 1 ? (n - 1) : 1);
    float repeat = (float)rep / den1;
    float per = (n >= 4) ? (float)per2 / (float)((n - 2) >= 1 ? (n - 2) : 1) : 0.f;
    float entz = (n > 1) ? ent : 0.f;
    float z = (n > 1) ? 1.f : 0.f;

    if (lane == 0) {
      ent_o[row] = entz;
      vlen_o[row] = (float)n;
      pat_o[row * 6 + 0] = repeat * z;
      pat_o[row * 6 + 1] = (float)incs / den1 * z;
      pat_o[row * 6 + 2] = (float)decs / den1 * z;
      pat_o[row * 6 + 3] = per * z;
      pat_o[row * 6 + 4] = (float)distinct * inv * z;
      pat_o[row * 6 + 5] = (float)maxrun * inv * z;
      cpx_o[row * 4 + 0] = (float)dc / den1 * z;
      cpx_o[row * 4 + 1] = entz / __logf((float)(n >= 2 ? n : 2)) * z;
      cpx_o[row * 4 + 2] = local * z;
      cpx_o[row * 4 + 3] = (1.f - repeat) * z;
    }
  }
}

// ---------------------------------------------------------------------------
// k_main: LSTM recurrence + prep2. 512-thread blocks (8 waves).
//   [0,512)    MFMA LSTM. fp16 G rows staged to LDS: ONE global_load_lds per
//              wave per step stages BOTH of its token rows (per-lane source
//              selects row r2+(lane>>5); 2x512B rows land contiguously in a
//              1040B-strided pair slot -- bank-uniform reads, half the bytes
//              and half the VMEM instrs of the f32 path). Lane's 16B G slice
//              = 8 f16 = both cells' gates, cvt'd into the two MFMA C-init
//              fragments. h hand-off = v_cvt_pk_bf16_f32 + single u32 write.
//   [512,640)  prep2: C1t = (A·B)^T, c1b fold.
// ---------------------------------------------------------------------------
#define LSTM_STEP(T)                                                           \
  {                                                                            \
    if ((T) < 59) {                                                            \
      const int tsn = dir ? (58 - (T)) : ((T) + 1);                            \
      unsigned int toff = tokoff[tsn * 16 + r2 + (lane >> 5)];                 \
      gload16(GbC + toff + ((lane & 31) << 4),                                 \
              Gm + (((T) + 1) & 1) * 8320 + w * 1040);                         \
    }                                                                          \
    const unsigned short* hb = hbuf[(T) & 1];                                  \
    short8 hf0 = *(const short8*)(hb + rdoff);                                 \
    short8 hf1 = *(const short8*)(hb + rdoff + 32);                            \
    const char* gbp = Gm + ((T) & 1) * 8320 + goffH;                           \
    h16x8 gvh = *(const h16x8*)(gbp);                                          \
    f32x4 acc0 = {(float)gvh[0], (float)gvh[1], (float)gvh[2], (float)gvh[3]}; \
    f32x4 acc1 = {(float)gvh[4], (float)gvh[5], (float)gvh[6], (float)gvh[7]}; \
    acc0 = __builtin_amdgcn_mfma_f32_16x16x32_bf16(bfr[0][0], hf0, acc0, 0, 0, 0); \
    acc1 = __builtin_amdgcn_mfma_f32_16x16x32_bf16(bfr[1][0], hf0, acc1, 0, 0, 0); \
    acc0 = __builtin_amdgcn_mfma_f32_16x16x32_bf16(bfr[0][1], hf1, acc0, 0, 0, 0); \
    acc1 = __builtin_amdgcn_mfma_f32_16x16x32_bf16(bfr[1][1], hf1, acc1, 0, 0, 0); \
    unsigned short* hw = hbuf[((T) + 1) & 1];                                  \
    float h0, h1;                                                              \
    {                                                                          \
      float Ef = ex2(-acc0[1]);                                                \
      float E1 = ex2(-acc0[0]);                                                \
      float E2 = ex2(acc0[2]);                                                 \
      float sf = __builtin_amdgcn_rcpf(1.f + Ef);                              \
      float p  = (E2 - 1.f) * __builtin_amdgcn_rcpf((1.f + E1) * (E2 + 1.f));  \
      float cn = fmaf(sf, cst0, p);                                            \
      cst0 = cn;                                                               \
      float E3 = ex2(-acc0[3]);                                                \
      float E4 = ex2(fminf(L2E2 * cn, 126.f));                                 \
      h0 = (E4 - 1.f) * __builtin_amdgcn_rcpf((1.f + E3) * (E4 + 1.f));        \
    }                                                                          \
    {                                                                          \
      float Ef = ex2(-acc1[1]);                                                \
      float E1 = ex2(-acc1[0]);                                                \
      float E2 = ex2(acc1[2]);                                                 \
      float sf = __builtin_amdgcn_rcpf(1.f + Ef);                              \
      float p  = (E2 - 1.f) * __builtin_amdgcn_rcpf((1.f + E1) * (E2 + 1.f));  \
      float cn = fmaf(sf, cst1, p);                                            \
      cst1 = cn;                                                               \
      float E3 = ex2(-acc1[3]);                                                \
      float E4 = ex2(fminf(L2E2 * cn, 126.f));                                 \
      h1 = (E4 - 1.f) * __builtin_amdgcn_rcpf((1.f + E3) * (E4 + 1.f));        \
    }                                                                          \
    unsigned int hp;                                                           \
    asm("v_cvt_pk_bf16_f32 %0, %1, %2" : "=v"(hp) : "v"(h0), "v"(h1));         \
    *(unsigned int*)(hw + wr0) = hp;                                           \
    if ((T) == 59) {                                                           \
      float2 o2; o2.x = h0; o2.y = h1;                                         \
      *(float2*)(hop) = o2;                                                    \
    }                                                                          \
    __syncthreads();                                                           \
  }

__global__ __launch_bounds__(512) void k_main(
    const int* __restrict__ x,
    const float* __restrict__ G_f, const float* __restrict__ G_r,
    const unsigned short* __restrict__ Wfrag,
    const float* __restrict__ A, const float* __restrict__ avb,
    const float* __restrict__ Bp, const float* __restrict__ vb,
    float* __restrict__ C1t, float* __restrict__ c1b,
    float* __restrict__ hf_o, float* __restrict__ hr_o) {
  __shared__ __align__(16) char Gm[2 * 8 * 1040];           // 16640 B
  __shared__ __align__(16) unsigned short hbuf[2][16 * 72]; // 4608 B
  __shared__ __align__(16) unsigned int tokoff[60 * 16];    // 3840 B
  const int bid = blockIdx.x;
  const int tid = threadIdx.x;

  if (bid < 512) {
    // ======================= LSTM recurrence =======================
    const int lane = tid & 63;
    const int w = tid >> 6;                      // wave id 0..7
    const int dir = bid >> 8;
    const int blk = bid & 255;
    const int b0 = blk << 4;
    const float* G = dir ? G_r : G_f;
    const char* GbC = (const char*)G;            // fp16 rows, 512B/token
    float* ho = dir ? hr_o : hf_o;

    for (int i = tid; i < 960; i += 512) {
      int r = i / 60, t = i - r * 60;
      tokoff[t * 16 + r] = ((unsigned int)x[(size_t)(b0 + r) * 60 + t]) << 9;
    }
    for (int i = tid; i < 16 * 72; i += 512) hbuf[0][i] = 0;

    // adjacent-unit A fragments: bfr[m][c]
    short8 bfr[2][2];
    #pragma unroll
    for (int m = 0; m < 2; m++)
      #pragma unroll
      for (int c = 0; c < 2; c++) {
        int idx = (((dir * 8 + w) * 2 + m) * 2 + c) * 64 + lane;
        bfr[m][c] = *(const short8*)(Wfrag + (size_t)idx * 8);
      }

    const int kg = lane >> 4;
    const int ln = lane & 15;                    // batch row within tile
    const int uA = w * 8 + kg * 2;               // cell-0 unit; cell-1 = uA+1
    const int rdoff = ln * 72 + kg * 8;          // h-frag read offset (shorts)
    const int wr0 = ln * 72 + uA;                // h write offset (shorts, u32)
    const int r2 = w * 2;                        // token-row pair this wave stages
    const int goffH = (ln >> 1) * 1040 + (ln & 1) * 512 + uA * 8;
    float* hop = ho + (size_t)(b0 + ln) * 64 + uA;
    float cst0 = 0.f, cst1 = 0.f;

    __syncthreads();   // tokoff + hbuf[0] visible

    // prologue: stage step-0 G row-pair into Gm[0]
    {
      const int ts0 = dir ? 59 : 0;
      unsigned int toff = tokoff[ts0 * 16 + r2 + (lane >> 5)];
      gload16(GbC + toff + ((lane & 31) << 4), Gm + w * 1040);
    }
    __syncthreads();   // drain prologue stage

    #pragma unroll 1
    for (int tt = 0; tt < 30; tt++) {
      const int t0 = tt * 2, t1 = tt * 2 + 1;
      LSTM_STEP(t0)
      LSTM_STEP(t1)
    }
  } else {
    // ======================= prep2 (head collapse) =======================
    const int i = bid - 512, j = tid;
    const float* Ar = A + (size_t)i * ADJ;
    if (j < 180) {
      float a0 = 0.f, a1 = 0.f, a2 = 0.f, a3 = 0.f;
      for (int k = 0; k < ADJ; k += 4) {
        a0 = fmaf(Ar[k],     Bp[(size_t)(k)     * 180 + j], a0);
        a1 = fmaf(Ar[k + 1], Bp[(size_t)(k + 1) * 180 + j], a1);
        a2 = fmaf(Ar[k + 2], Bp[(size_t)(k + 2) * 180 + j], a2);
        a3 = fmaf(Ar[k + 3], Bp[(size_t)(k + 3) * 180 + j], a3);
      }
      C1t[(size_t)j * 128 + i] = (a0 + a1) + (a2 + a3);
    } else if (j == 180) {
      float a0 = 0.f;
      for (int k = 0; k < ADJ; k++) a0 = fmaf(Ar[k], vb[k], a0);
      c1b[i] = a0 + avb[i];
    }
  }
}

// ---------------------------------------------------------------------------
// k_head: feature assembly + collapsed head. c-MLP L1 is a sparse gather:
// counts·W == sum_t W[x_t] (row 0 of c_w1t zeroed), 60 gathers vs 512 streams.
// 512 blocks x 256 threads, 8 rows/block.
// ---------------------------------------------------------------------------
#define FSTR 192

__global__ __launch_bounds__(256) void k_head(
    const int* __restrict__ x,
    const float* __restrict__ hf, const float* __restrict__ hr,
    const float* __restrict__ ent, const float* __restrict__ vlen,
    const float* __restrict__ pat, const float* __restrict__ cpx,
    const float* __restrict__ e_w1, const float* __restrict__ e_b1,
    const float* __restrict__ e_w2, const float* __restrict__ e_b2,
    const float* __restrict__ l_w1, const float* __restrict__ l_b1,
    const float* __restrict__ l_w2, const float* __restrict__ l_b2,
    const float* __restrict__ c_w1t, const float* __restrict__ c_b1,
    const float* __restrict__ c_w2, const float* __restrict__ c_b2,
    const float* __restrict__ p_w1, const float* __restrict__ p_b1,
    const float* __restrict__ p_w2, const float* __restrict__ p_b2,
    const float* __restrict__ x_w1, const float* __restrict__ x_b1,
    const float* __restrict__ x_w2, const float* __restrict__ x_b2,
    const float* __restrict__ C1t, const float* __restrict__ c1b,
    const float* __restrict__ g_w2t, const float* __restrict__ g_b2,
    const float* __restrict__ g_w3t, const float* __restrict__ g_b3,
    const float* __restrict__ g_w4t, const float* __restrict__ g_b4,
    float* __restrict__ out) {
  __shared__ float feat[8 * FSTR];
  __shared__ unsigned short tk[8 * 64];
  __shared__ float h1[8 * 128];
  __shared__ float h2[8 * 64];
  __shared__ float h3[8 * 32];
  __shared__ float h1c[8 * 33];
  __shared__ float lg[32];
  const int tid = threadIdx.x;
  const int b0 = blockIdx.x * 8;

  // h_f / h_r -> feat[0:128)
  if (tid < 128) {
    int r = tid >> 4, c = tid & 15;
    float4 vv = ((const float4*)(hf + (size_t)(b0 + r) * 64))[c];
    *(float4*)(feat + r * FSTR + c * 4) = vv;
  } else {
    int t = tid - 128;
    int r = t >> 4, c = t & 15;
    float4 vv = ((const float4*)(hr + (size_t)(b0 + r) * 64))[c];
    *(float4*)(feat + r * FSTR + 64 + c * 4) = vv;
  }
  // tokens -> LDS (8 rows x 60)
  for (int i = tid; i < 480; i += 256) {
    int r = i / 60, t = i - r * 60;
    tk[r * 64 + t] = (unsigned short)x[(size_t)(b0 + r) * 60 + t];
  }
  __syncthreads();
  // c-MLP layer 1 sparse: o = tid&31 (coalesced gather), r = tid>>5
  {
    int o = tid & 31, r = tid >> 5;
    const unsigned short* tkr = tk + r * 64;
    float a0 = 0.f, a1 = 0.f, a2 = 0.f, a3 = 0.f;
    #pragma unroll 5
    for (int t = 0; t < 60; t += 4) {
      int t0 = tkr[t], t1 = tkr[t + 1], t2 = tkr[t + 2], t3 = tkr[t + 3];
      a0 += c_w1t[t0 * 32 + o];
      a1 += c_w1t[t1 * 32 + o];
      a2 += c_w1t[t2 * 32 + o];
      a3 += c_w1t[t3 * 32 + o];
    }
    float invv = __builtin_amdgcn_rcpf(fmaxf(vlen[b0 + r], 1.f));
    h1c[r * 33 + o] = fmaxf(((a0 + a1) + (a2 + a3)) * invv + c_b1[o], 0.f);
  }
  __syncthreads();
  // small MLPs (threads 0..31) + c-MLP layer 2 (threads 64..191)
  if (tid < 32) {
    const int m = tid & 3, r = tid >> 2, b = b0 + r;
    float tt[24];
    if (m == 0) {
      float ein = ent[b] * 0.25f;
      #pragma unroll
      for (int o = 0; o < 16; o++) tt[o] = fmaxf(e_w1[o] * ein + e_b1[o], 0.f);
      #pragma unroll
      for (int o = 0; o < 8; o++) {
        float a = e_b2[o];
        #pragma unroll
        for (int k = 0; k < 16; k++) a = fmaf(e_w2[o * 16 + k], tt[k], a);
        feat[r * FSTR + 128 + o] = a;
      }
    } else if (m == 1) {
      float lin = vlen[b] * (1.f / 60.f);
      #pragma unroll
      for (int o = 0; o < 16; o++) tt[o] = fmaxf(l_w1[o] * lin + l_b1[o], 0.f);
      #pragma unroll
      for (int o = 0; o < 8; o++) {
        float a = l_b2[o];
        #pragma unroll
        for (int k = 0; k < 16; k++) a = fmaf(l_w2[o * 16 + k], tt[k], a);
        feat[r * FSTR + 136 + o] = a;
      }
    } else if (m == 2) {
      float pin[6];
      #pragma unroll
      for (int k = 0; k < 6; k++) pin[k] = pat[b * 6 + k];
      #pragma unroll
      for (int o = 0; o < 24; o++) {
        float a = p_b1[o];
        #pragma unroll
        for (int k = 0; k < 6; k++) a = fmaf(p_w1[o * 6 + k], pin[k], a);
        tt[o] = fmaxf(a, 0.f);
      }
      #pragma unroll
      for (int o = 0; o < 12; o++) {
        float a = p_b2[o];
        #pragma unroll
        for (int k = 0; k < 24; k++) a = fmaf(p_w2[o * 24 + k], tt[k], a);
        feat[r * FSTR + 160 + o] = a;
      }
    } else {
      float xin[4];
      #pragma unroll
      for (int k = 0; k < 4; k++) xin[k] = cpx[b * 4 + k];
      #pragma unroll
      for (int o = 0; o < 16; o++) {
        float a = x_b1[o];
        #pragma unroll
        for (int k = 0; k < 4; k++) a = fmaf(x_w1[o * 4 + k], xin[k], a);
        tt[o] = fmaxf(a, 0.f);
      }
      #pragma unroll
      for (int o = 0; o < 8; o++) {
        float a = x_b2[o];
        #pragma unroll
        for (int k = 0; k < 16; k++) a = fmaf(x_w2[o * 16 + k], tt[k], a);
        feat[r * FSTR + 172 + o] = a;
      }
    }
  } else if (tid >= 64 && tid < 192) {
    int t = tid - 64;
    int r = t >> 4, o = t & 15;
    float a = c_b2[o];
    const float* hh = h1c + r * 33;
    #pragma unroll
    for (int k = 0; k < 32; k++) a = fmaf(c_w2[o * 32 + k], hh[k], a);
    feat[r * FSTR + 144 + o] = a;
  }
  __syncthreads();

  // L1: 180 -> 128 relu. C1t lane-coalesced, feat b128 broadcasts.
  {
    const int o = tid & 127, rg = tid >> 7;
    const float* f0p = feat + (rg * 4 + 0) * FSTR;
    const float* f1p = feat + (rg * 4 + 1) * FSTR;
    const float* f2p = feat + (rg * 4 + 2) * FSTR;
    const float* f3p = feat + (rg * 4 + 3) * FSTR;
    float a0 = 0.f, a1 = 0.f, a2 = 0.f, a3 = 0.f;
    #pragma unroll 3
    for (int k4 = 0; k4 < 45; k4++) {
      float w0 = C1t[(size_t)(k4 * 4 + 0) * 128 + o];
      float w1 = C1t[(size_t)(k4 * 4 + 1) * 128 + o];
      float w2 = C1t[(size_t)(k4 * 4 + 2) * 128 + o];
      float w3 = C1t[(size_t)(k4 * 4 + 3) * 128 + o];
      float4 f0 = *(const float4*)(f0p + k4 * 4);
      float4 f1 = *(const float4*)(f1p + k4 * 4);
      float4 f2 = *(const float4*)(f2p + k4 * 4);
      float4 f3 = *(const float4*)(f3p + k4 * 4);
      a0 = fmaf(w0, f0.x, a0); a0 = fmaf(w1, f0.y, a0);
      a0 = fmaf(w2, f0.z, a0); a0 = fmaf(w3, f0.w, a0);
      a1 = fmaf(w0, f1.x, a1); a1 = fmaf(w1, f1.y, a1);
      a1 = fmaf(w2, f1.z, a1); a1 = fmaf(w3, f1.w, a1);
      a2 = fmaf(w0, f2.x, a2); a2 = fmaf(w1, f2.y, a2);
      a2 = fmaf(w2, f2.z, a2); a2 = fmaf(w3, f2.w, a2);
      a3 = fmaf(w0, f3.x, a3); a3 = fmaf(w1, f3.y, a3);
      a3 = fmaf(w2, f3.z, a3); a3 = fmaf(w3, f3.w, a3);
    }
    float bb = c1b[o];
    h1[(rg * 4 + 0) * 128 + o] = fmaxf(a0 + bb, 0.f);
    h1[(rg * 4 + 1) * 128 + o] = fmaxf(a1 + bb, 0.f);
    h1[(rg * 4 + 2) * 128 + o] = fmaxf(a2 + bb, 0.f);
    h1[(rg * 4 + 3) * 128 + o] = fmaxf(a3 + bb, 0.f);
  }
  __syncthreads();
  // L2: 128 -> 64 relu
  {
    const int o = tid & 63, rg = tid >> 6;
    const float* f0p = h1 + (rg * 2 + 0) * 128;
    const float* f1p = h1 + (rg * 2 + 1) * 128;
    float a0 = 0.f, a1 = 0.f;
    #pragma unroll 4
    for (int k4 = 0; k4 < 32; k4++) {
      float w0 = g_w2t[(k4 * 4 + 0) * 64 + o];
      float w1 = g_w2t[(k4 * 4 + 1) * 64 + o];
      float w2 = g_w2t[(k4 * 4 + 2) * 64 + o];
      float w3 = g_w2t[(k4 * 4 + 3) * 64 + o];
      float4 f0 = *(const float4*)(f0p + k4 * 4);
      float4 f1 = *(const float4*)(f1p + k4 * 4);
      a0 = fmaf(w0, f0.x, a0); a0 = fmaf(w1, f0.y, a0);
      a0 = fmaf(w2, f0.z, a0); a0 = fmaf(w3, f0.w, a0);
      a1 = fmaf(w0, f1.x, a1); a1 = fmaf(w1, f1.y, a1);
      a1 = fmaf(w2, f1.z, a1); a1 = fmaf(w3, f1.w, a1);
    }
    float bb = g_b2[o];
    h2[(rg * 2 + 0) * 64 + o] = fmaxf(a0 + bb, 0.f);
    h2[(rg * 2 + 1) * 64 + o] = fmaxf(a1 + bb, 0.f);
  }
  __syncthreads();
  // L3: 64 -> 32 relu
  {
    const int o = tid & 31, rg = tid >> 5;
    const float* fp = h2 + rg * 64;
    float a = 0.f;
    #pragma unroll 4
    for (int k4 = 0; k4 < 16; k4++) {
      float w0 = g_w3t[(k4 * 4 + 0) * 32 + o];
      float w1 = g_w3t[(k4 * 4 + 1) * 32 + o];
      float w2 = g_w3t[(k4 * 4 + 2) * 32 + o];
      float w3 = g_w3t[(k4 * 4 + 3) * 32 + o];
      float4 f0 = *(const float4*)(fp + k4 * 4);
      a = fmaf(w0, f0.x, a); a = fmaf(w1, f0.y, a);
      a = fmaf(w2, f0.z, a); a = fmaf(w3, f0.w, a);
    }
    h3[rg * 32 + o] = fmaxf(a + g_b3[o], 0.f);
  }
  __syncthreads();
  // L4: 32 -> 4 logits
  if (tid < 32) {
    int r = tid >> 2, o = tid & 3;
    const float* hh = h3 + r * 32;
    float a = g_b4[o];
    #pragma unroll
    for (int k = 0; k < 32; k++) a = fmaf(g_w4t[k * 4 + o], hh[k], a);
    lg[tid] = a;
  }
  __syncthreads();
  if (tid < 8) {
    float l0 = lg[tid * 4 + 0], l1 = lg[tid * 4 + 1];
    float l2 = lg[tid * 4 + 2], l3 = lg[tid * 4 + 3];
    float m = fmaxf(fmaxf(l0, l1), fmaxf(l2, l3));
    float e0 = __expf(l0 - m), e1 = __expf(l1 - m);
    float e2 = __expf(l2 - m), e3 = __expf(l3 - m);
    float is = __builtin_amdgcn_rcpf(e0 + e1 + e2 + e3);
    float4 o4; o4.x = e0 * is; o4.y = e1 * is; o4.z = e2 * is; o4.w = e3 * is;
    *(float4*)(out + (size_t)(b0 + tid) * 4) = o4;
  }
}

// ---------------------------------------------------------------------------
extern "C" void kernel_launch(void* const* d_in, const int* in_sizes, int n_in,
                              void* d_out, int out_size, void* d_ws, size_t ws_size,
                              hipStream_t stream) {
  const int*   x     = (const int*)d_in[0];
  const float* emb   = (const float*)d_in[1];
  const float* wih_f = (const float*)d_in[2];
  const float* whh_f = (const float*)d_in[3];
  const float* bih_f = (const float*)d_in[4];
  const float* bhh_f = (const float*)d_in[5];
  const float* wih_r = (const float*)d_in[6];
  const float* whh_r = (const float*)d_in[7];
  const float* bih_r = (const float*)d_in[8];
  const float* bhh_r = (const float*)d_in[9];
  const float* e_w1 = (const float*)d_in[10]; const float* e_b1 = (const float*)d_in[11];
  const float* e_w2 = (const float*)d_in[12]; const float* e_b2 = (const float*)d_in[13];
  const float* l_w1 = (const float*)d_in[14]; const float* l_b1 = (const float*)d_in[15];
  const float* l_w2 = (const float*)d_in[16]; const float* l_b2 = (const float*)d_in[17];
  const float* c_w1 = (const float*)d_in[18]; const float* c_b1 = (const float*)d_in[19];
  const float* c_w2 = (const float*)d_in[20]; const float* c_b2 = (const float*)d_in[21];
  const float* p_w1 = (const float*)d_in[22]; const float* p_b1 = (const float*)d_in[23];
  const float* p_w2 = (const float*)d_in[24]; const float* p_b2 = (const float*)d_in[25];
  const float* x_w1 = (const float*)d_in[26]; const float* x_b1 = (const float*)d_in[27];
  const float* x_w2 = (const float*)d_in[28]; const float* x_b2 = (const float*)d_in[29];
  const float* fp_w = (const float*)d_in[30]; const float* fp_b = (const float*)d_in[31];
  const float* attn_w = (const float*)d_in[32]; const float* attn_b = (const float*)d_in[33];
  const float* out_w = (const float*)d_in[34]; const float* out_b = (const float*)d_in[35];
  const float* g_w1 = (const float*)d_in[36]; const float* g_b1 = (const float*)d_in[37];
  const float* g_w2 = (const float*)d_in[38]; const float* g_b2 = (const float*)d_in[39];
  const float* g_w3 = (const float*)d_in[40]; const float* g_b3 = (const float*)d_in[41];
  const float* g_w4 = (const float*)d_in[42]; const float* g_b4 = (const float*)d_in[43];

  float* ws   = (float*)d_ws;
  float* G_f  = ws;                       // fp16 512*256 (fits in 512*256 f32 slot)
  float* G_r  = G_f  + 512 * 256;
  float* hfw  = G_r  + 512 * 256;         // B*64
  float* hrw  = hfw  + BATCH * 64;
  float* entw = hrw  + BATCH * 64;        // B
  float* vlnw = entw + BATCH;
  float* patw = vlnw + BATCH;             // B*6
  float* cpxw = patw + BATCH * 6;         // B*4
  float* Aw   = cpxw + BATCH * 4;         // 128*184
  float* avbw = Aw + 128 * ADJ;           // 128
  float* Bpw  = avbw + 128;               // 184*180
  float* vbw  = Bpw + ADJ * 180;          // 184
  float* C1t  = vbw + ADJ;                // 180*128
  float* c1b  = C1t + 180 * 128;          // 128
  float* g2t  = c1b + 128;                // 128*64
  float* g3t  = g2t + 128 * 64;           // 64*32
  float* g4t  = g3t + 64 * 32;            // 32*4
  float* cw1t = g4t + 32 * 4;             // 512*32
  unsigned short* Wfrag = (unsigned short*)(cw1t + 512 * 32);  // 32768 bf16

  k_prep<<<dim3(465 + BATCH / 4), dim3(256), 0, stream>>>(
      x, emb, wih_f, bih_f, bhh_f, wih_r, bih_r, bhh_r, whh_f, whh_r,
      g_w1, g_b1, out_w, out_b, attn_w, attn_b, fp_w, fp_b,
      g_w2, g_w3, g_w4, c_w1,
      G_f, G_r, Wfrag, Aw, avbw, Bpw, vbw, g2t, g3t, g4t, cw1t,
      entw, vlnw, patw, cpxw);
  k_main<<<dim3(640), dim3(512), 0, stream>>>(
      x, G_f, G_r, Wfrag, Aw, avbw, Bpw, vbw, C1t, c1b, hfw, hrw);
  k_head<<<dim3(BATCH / 8), dim3(256), 0, stream>>>(
      x, hfw, hrw, entw, vlnw, patw, cpxw,
      e_w1, e_b1, e_w2, e_b2, l_w1, l_b1, l_w2, l_b2,
      cw1t, c_b1, c_w2, c_b2, p_w1, p_b1, p_w2, p_b2,
      x_w1, x_b1, x_w2, x_b2, C1t, c1b,
      g2t, g_b2, g3t, g_b3, g4t, g_b4,
      (float*)d_out);
}